// Round 1
// baseline (3484.130 us; speedup 1.0000x reference)
//
#include <hip/hip_runtime.h>
#include <hip/hip_bf16.h>
#include <math.h>

#define T_TOK 4096
#define HIDDEN 2048
#define NH 16
#define NKVH 2
#define HD 128
#define NSEG 8

// ---------------- fp32 tiled GEMM: C = A(MxK) @ B(KxN) + bias ----------------
#define BM 64
#define BN 64
#define BK 16

__global__ __launch_bounds__(256) void gemm_f32(const float* __restrict__ A,
                                                const float* __restrict__ B,
                                                const float* __restrict__ bias,
                                                float* __restrict__ C,
                                                int M, int N, int K)
{
    __shared__ float As[BK][BM + 1];
    __shared__ float Bs[BK][BN + 1];
    const int tid = threadIdx.x;
    const int tx = tid & 15, ty = tid >> 4;
    const int brow = blockIdx.y * BM, bcol = blockIdx.x * BN;
    float acc[4][4] = {};
    for (int k0 = 0; k0 < K; k0 += BK) {
        #pragma unroll
        for (int i = 0; i < 4; ++i) {           // A tile: 64 rows x 16 k
            int idx = tid + i * 256;
            int r = idx >> 4;
            int c = idx & 15;
            As[c][r] = A[(size_t)(brow + r) * K + k0 + c];
        }
        #pragma unroll
        for (int i = 0; i < 4; ++i) {           // B tile: 16 k x 64 cols
            int idx = tid + i * 256;
            int r = idx >> 6;
            int c = idx & 63;
            Bs[r][c] = B[(size_t)(k0 + r) * N + bcol + c];
        }
        __syncthreads();
        #pragma unroll
        for (int kk = 0; kk < BK; ++kk) {
            float a[4], b[4];
            #pragma unroll
            for (int i = 0; i < 4; ++i) a[i] = As[kk][ty * 4 + i];
            #pragma unroll
            for (int j = 0; j < 4; ++j) b[j] = Bs[kk][tx * 4 + j];
            #pragma unroll
            for (int i = 0; i < 4; ++i)
                #pragma unroll
                for (int j = 0; j < 4; ++j)
                    acc[i][j] += a[i] * b[j];
        }
        __syncthreads();
    }
    #pragma unroll
    for (int i = 0; i < 4; ++i) {
        int r = brow + ty * 4 + i;
        #pragma unroll
        for (int j = 0; j < 4; ++j) {
            int c = bcol + tx * 4 + j;
            float val = acc[i][j];
            if (bias) val += bias[c];
            C[(size_t)r * N + c] = val;
        }
    }
}

// ---------------- RoPE (rotate-half), positions restart per sequence --------
__global__ void rope_kernel(float* __restrict__ q, float* __restrict__ k,
                            const int* __restrict__ pos_ids,
                            const float* __restrict__ inv_freq)
{
    const int t = blockIdx.x;
    const int hh = blockIdx.y;   // 0..NH+NKVH-1
    const int i = threadIdx.x;   // 0..63 (pair index)
    const float p = (float)pos_ids[t];
    const float f = p * inv_freq[i];
    const float c = cosf(f), s = sinf(f);
    float* base;
    if (hh < NH) base = q + ((size_t)t * NH + hh) * HD;
    else         base = k + ((size_t)t * NKVH + (hh - NH)) * HD;
    const float x1 = base[i];
    const float x2 = base[i + 64];
    base[i]      = x1 * c - x2 * s;
    base[i + 64] = x2 * c + x1 * s;
}

// ---------------- varlen causal GQA flash attention (fp32) ------------------
#define QT 32
#define KT 32

__global__ __launch_bounds__(256) void attn_kernel(const float* __restrict__ q,
                                                   const float* __restrict__ k,
                                                   const float* __restrict__ v,
                                                   const int* __restrict__ cu,
                                                   float* __restrict__ out)
{
    __shared__ float Qs[QT][HD + 1];
    __shared__ float Ks[KT][HD + 1];
    __shared__ float Vs[KT][HD + 1];
    __shared__ float Ps[QT][KT + 1];

    const int tid = threadIdx.x;
    const int h = blockIdx.y;
    const int kvh = h >> 3;          // h / (NH/NKVH)
    const int q0 = blockIdx.x * QT;
    const int ty = tid >> 3;         // q row 0..31
    const int tx = tid & 7;

    const float scale = 0.08838834764831845f;  // 1/sqrt(128)
    for (int idx = tid; idx < QT * HD; idx += 256) {
        int r = idx >> 7, d = idx & 127;
        Qs[r][d] = q[((size_t)(q0 + r) * NH + h) * HD + d] * scale;
    }

    const int qg = q0 + ty;
    int seg = 0;
    #pragma unroll
    for (int j = 1; j <= NSEG; ++j) seg += (cu[j] <= qg) ? 1 : 0;
    const int seg_start = cu[seg];

    int seg0 = 0;
    #pragma unroll
    for (int j = 1; j <= NSEG; ++j) seg0 += (cu[j] <= q0) ? 1 : 0;
    const int s_begin = cu[seg0] & ~(KT - 1);   // block-uniform

    float m = -1e30f, l = 0.f;
    float acc[16];
    #pragma unroll
    for (int i = 0; i < 16; ++i) acc[i] = 0.f;

    __syncthreads();

    for (int s0 = s_begin; s0 <= q0 + QT - 1; s0 += KT) {
        for (int idx = tid; idx < KT * HD; idx += 256) {
            int r = idx >> 7, d = idx & 127;
            int s = s0 + r;
            float kk_ = 0.f, vv = 0.f;
            if (s < T_TOK) {
                kk_ = k[((size_t)s * NKVH + kvh) * HD + d];
                vv  = v[((size_t)s * NKVH + kvh) * HD + d];
            }
            Ks[r][d] = kk_;
            Vs[r][d] = vv;
        }
        __syncthreads();

        float sc[4];
        #pragma unroll
        for (int j = 0; j < 4; ++j) {
            const int c = tx * 4 + j;
            const int s = s0 + c;
            const bool valid = (s >= seg_start) && (s <= qg);
            float dot = 0.f;
            if (valid) {
                #pragma unroll 8
                for (int d = 0; d < HD; ++d) dot += Qs[ty][d] * Ks[c][d];
            }
            sc[j] = valid ? dot : -1e30f;
        }
        float mx = fmaxf(fmaxf(sc[0], sc[1]), fmaxf(sc[2], sc[3]));
        #pragma unroll
        for (int o = 1; o < 8; o <<= 1) mx = fmaxf(mx, __shfl_xor(mx, o, 64));

        if (mx > -1e29f) {
            const float m_new = fmaxf(m, mx);
            const float sc_old = __expf(m - m_new);
            float psum = 0.f;
            #pragma unroll
            for (int j = 0; j < 4; ++j) {
                float p = (sc[j] > -1e29f) ? __expf(sc[j] - m_new) : 0.f;
                Ps[ty][tx * 4 + j] = p;
                psum += p;
            }
            #pragma unroll
            for (int o = 1; o < 8; o <<= 1) psum += __shfl_xor(psum, o, 64);
            l = l * sc_old + psum;
            m = m_new;
            #pragma unroll
            for (int i = 0; i < 16; ++i) acc[i] *= sc_old;
        } else {
            #pragma unroll
            for (int j = 0; j < 4; ++j) Ps[ty][tx * 4 + j] = 0.f;
        }
        __syncthreads();

        #pragma unroll 4
        for (int kk = 0; kk < KT; ++kk) {
            const float p = Ps[ty][kk];
            #pragma unroll
            for (int i = 0; i < 16; ++i)
                acc[i] += p * Vs[kk][tx * 16 + i];
        }
        __syncthreads();
    }

    const float inv_l = 1.f / l;
    #pragma unroll
    for (int i = 0; i < 16; ++i)
        out[((size_t)qg * NH + h) * HD + tx * 16 + i] = acc[i] * inv_l;
}

extern "C" void kernel_launch(void* const* d_in, const int* in_sizes, int n_in,
                              void* d_out, int out_size, void* d_ws, size_t ws_size,
                              hipStream_t stream)
{
    const float* hs       = (const float*)d_in[0];
    const int*   pos      = (const int*)d_in[1];
    const int*   cu       = (const int*)d_in[2];
    const float* inv_freq = (const float*)d_in[3];
    const float* Wq       = (const float*)d_in[4];
    const float* bq       = (const float*)d_in[5];
    const float* Wk       = (const float*)d_in[6];
    const float* bk       = (const float*)d_in[7];
    const float* Wv       = (const float*)d_in[8];
    const float* bv       = (const float*)d_in[9];
    const float* Wo       = (const float*)d_in[10];
    float* out = (float*)d_out;

    float* qb = (float*)d_ws;                               // T * NH * HD
    float* kb = qb + (size_t)T_TOK * NH * HD;               // T * NKVH * HD
    float* vb = kb + (size_t)T_TOK * NKVH * HD;             // T * NKVH * HD
    float* ab = vb + (size_t)T_TOK * NKVH * HD;             // T * NH * HD

    dim3 blk(256);
    gemm_f32<<<dim3((NH * HD) / BN, T_TOK / BM), blk, 0, stream>>>(
        hs, Wq, bq, qb, T_TOK, NH * HD, HIDDEN);
    gemm_f32<<<dim3((NKVH * HD) / BN, T_TOK / BM), blk, 0, stream>>>(
        hs, Wk, bk, kb, T_TOK, NKVH * HD, HIDDEN);
    gemm_f32<<<dim3((NKVH * HD) / BN, T_TOK / BM), blk, 0, stream>>>(
        hs, Wv, bv, vb, T_TOK, NKVH * HD, HIDDEN);

    rope_kernel<<<dim3(T_TOK, NH + NKVH), dim3(64), 0, stream>>>(qb, kb, pos, inv_freq);

    attn_kernel<<<dim3(T_TOK / QT, NH), blk, 0, stream>>>(qb, kb, vb, cu, ab);

    gemm_f32<<<dim3(HIDDEN / BN, T_TOK / BM), blk, 0, stream>>>(
        ab, Wo, nullptr, out, T_TOK, HIDDEN, HIDDEN);
}

// Round 2
// 424.015 us; speedup vs baseline: 8.2170x; 8.2170x over previous
//
#include <hip/hip_runtime.h>
#include <math.h>

#define T_TOK 4096
#define HIDDEN 2048
#define NH 16
#define NKVH 2
#define HD 128
#define NSEG 8

typedef __attribute__((ext_vector_type(8))) short bf16x8;
typedef __attribute__((ext_vector_type(4))) float f32x4;

__device__ __forceinline__ unsigned short f2bf(float f) {
    union { float f; unsigned u; } x; x.f = f;
    unsigned r = x.u + 0x7FFF + ((x.u >> 16) & 1);
    return (unsigned short)(r >> 16);
}
__device__ __forceinline__ float bf2f(unsigned short u) {
    union { unsigned u; float f; } x; x.u = ((unsigned)u) << 16;
    return x.f;
}

__device__ __forceinline__ void gload16(const void* g, void* l) {
    __builtin_amdgcn_global_load_lds(
        (const __attribute__((address_space(1))) unsigned int*)g,
        (__attribute__((address_space(3))) unsigned int*)l, 16, 0, 0);
}

// ---------- fp32 -> bf16 elementwise ----------
__global__ void conv_bf16(const float* __restrict__ in, unsigned short* __restrict__ out, int n)
{
    int i = (blockIdx.x * 256 + threadIdx.x) * 4;
    if (i + 3 < n) {
        float4 v = *(const float4*)&in[i];
        ushort4 o;
        o.x = f2bf(v.x); o.y = f2bf(v.y); o.z = f2bf(v.z); o.w = f2bf(v.w);
        *(ushort4*)&out[i] = o;
    }
}

// ---------- W [K][N] fp32 -> WT [N][K] bf16 ----------
__global__ void transpose_w(const float* __restrict__ W, unsigned short* __restrict__ WT,
                            int K, int N)
{
    __shared__ float tile[32][33];
    const int k0 = blockIdx.y * 32, n0 = blockIdx.x * 32;
    const int c = threadIdx.x & 31, r0 = threadIdx.x >> 5;
    #pragma unroll
    for (int r = r0; r < 32; r += 8)
        tile[r][c] = W[(size_t)(k0 + r) * N + n0 + c];
    __syncthreads();
    #pragma unroll
    for (int r = r0; r < 32; r += 8)
        WT[(size_t)(n0 + r) * K + k0 + c] = f2bf(tile[c][r]);
}

// ---------- vb [T][256] bf16 -> vt [256][T] bf16 ----------
__global__ void transpose_v(const unsigned short* __restrict__ vb, unsigned short* __restrict__ vt)
{
    __shared__ unsigned short tile[64][66];
    const int t0 = blockIdx.y * 64, d0 = blockIdx.x * 64;
    const int c = threadIdx.x & 63, r0 = threadIdx.x >> 6;
    #pragma unroll
    for (int r = r0; r < 64; r += 4)
        tile[r][c] = vb[(size_t)(t0 + r) * (NKVH * HD) + d0 + c];
    __syncthreads();
    #pragma unroll
    for (int r = r0; r < 64; r += 4)
        vt[(size_t)(d0 + r) * T_TOK + t0 + c] = tile[c][r];
}

// ---------- RoPE on bf16 q/k, fp32 math ----------
__global__ void rope_kernel(unsigned short* __restrict__ q, unsigned short* __restrict__ k,
                            const int* __restrict__ pos_ids, const float* __restrict__ inv_freq)
{
    const int t = blockIdx.x, hh = blockIdx.y, i = threadIdx.x;
    const float p = (float)pos_ids[t];
    const float f = p * inv_freq[i];
    const float c = cosf(f), s = sinf(f);
    unsigned short* base = (hh < NH) ? q + ((size_t)t * NH + hh) * HD
                                     : k + ((size_t)t * NKVH + (hh - NH)) * HD;
    const float x1 = bf2f(base[i]);
    const float x2 = bf2f(base[i + 64]);
    base[i]      = f2bf(x1 * c - x2 * s);
    base[i + 64] = f2bf(x2 * c + x1 * s);
}

// ---------- bf16 MFMA GEMM: C[M][N] = A[M][K] * BT[N][K]^T (+bias) ----------
// LDS layout per 128x32 tile: [8 rtile][4 kblk][16 row][8 k] (linear for global_load_lds)
template<bool BF16_OUT>
__global__ __launch_bounds__(256) void gemm_bt(const unsigned short* __restrict__ A,
                                               const unsigned short* __restrict__ BT,
                                               const float* __restrict__ bias,
                                               void* __restrict__ Cout,
                                               int N, int K)
{
    __shared__ unsigned short Alds[4096];   // 8 KB
    __shared__ unsigned short Blds[4096];
    const int tid = threadIdx.x;
    const int l = tid & 63, w = tid >> 6;
    const int wr = w >> 1, wc = w & 1;
    const int lr = l & 15, lk = l >> 4;
    const int brow = blockIdx.y * 128, bcol = blockIdx.x * 128;

    f32x4 acc[4][4];
    #pragma unroll
    for (int m = 0; m < 4; ++m)
        #pragma unroll
        for (int n = 0; n < 4; ++n)
            acc[m][n] = f32x4{0.f, 0.f, 0.f, 0.f};

    for (int k0 = 0; k0 < K; k0 += 32) {
        __syncthreads();
        gload16(A + (size_t)(brow + w * 16 + lr) * K + k0 + lk * 8,        Alds + w * 512);
        gload16(A + (size_t)(brow + (w + 4) * 16 + lr) * K + k0 + lk * 8,  Alds + (w + 4) * 512);
        gload16(BT + (size_t)(bcol + w * 16 + lr) * K + k0 + lk * 8,       Blds + w * 512);
        gload16(BT + (size_t)(bcol + (w + 4) * 16 + lr) * K + k0 + lk * 8, Blds + (w + 4) * 512);
        __syncthreads();
        bf16x8 av[4], bv[4];
        #pragma unroll
        for (int m = 0; m < 4; ++m)
            av[m] = *(const bf16x8*)&Alds[(wr * 4 + m) * 512 + lk * 128 + lr * 8];
        #pragma unroll
        for (int n = 0; n < 4; ++n)
            bv[n] = *(const bf16x8*)&Blds[(wc * 4 + n) * 512 + lk * 128 + lr * 8];
        #pragma unroll
        for (int m = 0; m < 4; ++m)
            #pragma unroll
            for (int n = 0; n < 4; ++n)
                acc[m][n] = __builtin_amdgcn_mfma_f32_16x16x32_bf16(av[m], bv[n], acc[m][n], 0, 0, 0);
    }

    #pragma unroll
    for (int m = 0; m < 4; ++m) {
        const int row = brow + wr * 64 + m * 16 + lk * 4;
        #pragma unroll
        for (int n = 0; n < 4; ++n) {
            const int col = bcol + wc * 64 + n * 16 + lr;
            const float bb = bias ? bias[col] : 0.f;
            #pragma unroll
            for (int j = 0; j < 4; ++j) {
                const float vv = acc[m][n][j] + bb;
                if constexpr (BF16_OUT)
                    ((unsigned short*)Cout)[(size_t)(row + j) * N + col] = f2bf(vv);
                else
                    ((float*)Cout)[(size_t)(row + j) * N + col] = vv;
            }
        }
    }
}

// ---------- varlen causal GQA flash attention, bf16 MFMA ----------
// block: 64 q-rows x 1 head; 4 waves, wave w owns qtile w (16 rows); KB=32
__global__ __launch_bounds__(256) void attn_mfma(const unsigned short* __restrict__ qb,
                                                 const unsigned short* __restrict__ kb,
                                                 const unsigned short* __restrict__ vt,
                                                 const int* __restrict__ cu,
                                                 unsigned short* __restrict__ ob)
{
    __shared__ unsigned short Qlds[8192];      // [4 qt][16 dblk][16 q][8] = 16 KB
    __shared__ unsigned short Klds[4096];      // [2 st][16 dblk][16 s][8] = 8 KB
    __shared__ unsigned short Vlds[4096];      // [8 dt][4 sblk][16 d][8] = 8 KB
    __shared__ unsigned short Plds[4 * 16 * 40]; // per-wave [16 q][40] (pad) = 5 KB

    const int tid = threadIdx.x;
    const int l = tid & 63, w = tid >> 6;
    const int lr = l & 15, lk = l >> 4;
    const int h = blockIdx.y, kvh = h >> 3;
    const int q0 = blockIdx.x * 64;
    const float SCALE = 0.08838834764831845f;

    // stage own qtile
    #pragma unroll
    for (int i = 0; i < 4; ++i)
        gload16(qb + ((size_t)(q0 + w * 16 + lr) * NH + h) * HD + (i * 4 + lk) * 8,
                Qlds + w * 2048 + i * 512);

    const int qrow = q0 + w * 16 + lk * 4;   // rows qrow..qrow+3 for this lane
    int seg_lo[4];
    #pragma unroll
    for (int j = 0; j < 4; ++j) {
        int s = 0;
        #pragma unroll
        for (int x = 1; x < NSEG; ++x) s = (cu[x] <= qrow + j) ? cu[x] : s;
        seg_lo[j] = s;
    }
    int sb = 0;
    #pragma unroll
    for (int x = 1; x < NSEG; ++x) sb = (cu[x] <= q0) ? cu[x] : sb;
    sb &= ~31;

    float m_r[4], l_r[4];
    #pragma unroll
    for (int j = 0; j < 4; ++j) { m_r[j] = -1e30f; l_r[j] = 0.f; }
    f32x4 oacc[8];
    #pragma unroll
    for (int d = 0; d < 8; ++d) oacc[d] = f32x4{0.f, 0.f, 0.f, 0.f};

    __syncthreads();   // Q staged (barrier drains vmcnt)

    const int send = q0 + 63;
    for (int s0 = sb; s0 <= send; s0 += 32) {
        // stage K (issues w, w+4) and Vt (issues w, w+4)
        {
            const int i0 = w, i1 = w + 4;
            gload16(kb + ((size_t)(s0 + (i0 >> 2) * 16 + lr) * NKVH + kvh) * HD + ((i0 & 3) * 4 + lk) * 8,
                    Klds + i0 * 512);
            gload16(kb + ((size_t)(s0 + (i1 >> 2) * 16 + lr) * NKVH + kvh) * HD + ((i1 & 3) * 4 + lk) * 8,
                    Klds + i1 * 512);
            gload16(vt + (size_t)(kvh * HD + i0 * 16 + lr) * T_TOK + s0 + lk * 8,
                    Vlds + i0 * 512);
            gload16(vt + (size_t)(kvh * HD + i1 * 16 + lr) * T_TOK + s0 + lk * 8,
                    Vlds + i1 * 512);
        }
        __syncthreads();

        // S = Q K^T  (2 col-tiles x 4 k-steps)
        f32x4 sacc[2];
        sacc[0] = f32x4{0.f, 0.f, 0.f, 0.f};
        sacc[1] = f32x4{0.f, 0.f, 0.f, 0.f};
        #pragma unroll
        for (int kk = 0; kk < 4; ++kk) {
            bf16x8 aq = *(const bf16x8*)&Qlds[w * 2048 + (kk * 4 + lk) * 128 + lr * 8];
            sacc[0] = __builtin_amdgcn_mfma_f32_16x16x32_bf16(
                aq, *(const bf16x8*)&Klds[0 * 2048 + (kk * 4 + lk) * 128 + lr * 8], sacc[0], 0, 0, 0);
            sacc[1] = __builtin_amdgcn_mfma_f32_16x16x32_bf16(
                aq, *(const bf16x8*)&Klds[1 * 2048 + (kk * 4 + lk) * 128 + lr * 8], sacc[1], 0, 0, 0);
        }

        // online softmax (per lane: rows qrow..qrow+3, cols s0+lr, s0+16+lr)
        float al[4];
        #pragma unroll
        for (int j = 0; j < 4; ++j) {
            const int qg = qrow + j;
            const int sg0 = s0 + lr, sg1 = s0 + 16 + lr;
            const bool v0 = (sg0 >= seg_lo[j]) && (sg0 <= qg);
            const bool v1 = (sg1 >= seg_lo[j]) && (sg1 <= qg);
            float x0 = v0 ? sacc[0][j] * SCALE : -1e30f;
            float x1 = v1 ? sacc[1][j] * SCALE : -1e30f;
            float t = fmaxf(x0, x1);
            t = fmaxf(t, __shfl_xor(t, 1));
            t = fmaxf(t, __shfl_xor(t, 2));
            t = fmaxf(t, __shfl_xor(t, 4));
            t = fmaxf(t, __shfl_xor(t, 8));
            const float mn = fmaxf(m_r[j], t);
            const float a = __expf(m_r[j] - mn);
            const float p0 = v0 ? __expf(x0 - mn) : 0.f;
            const float p1 = v1 ? __expf(x1 - mn) : 0.f;
            float ps = p0 + p1;
            ps += __shfl_xor(ps, 1);
            ps += __shfl_xor(ps, 2);
            ps += __shfl_xor(ps, 4);
            ps += __shfl_xor(ps, 8);
            l_r[j] = l_r[j] * a + ps;
            m_r[j] = mn;
            al[j] = a;
            Plds[w * 640 + (lk * 4 + j) * 40 + lr]      = f2bf(p0);
            Plds[w * 640 + (lk * 4 + j) * 40 + 16 + lr] = f2bf(p1);
        }
        #pragma unroll
        for (int dt = 0; dt < 8; ++dt) {
            oacc[dt][0] *= al[0]; oacc[dt][1] *= al[1];
            oacc[dt][2] *= al[2]; oacc[dt][3] *= al[3];
        }
        // PV
        bf16x8 pa = *(const bf16x8*)&Plds[w * 640 + lr * 40 + lk * 8];
        #pragma unroll
        for (int dt = 0; dt < 8; ++dt) {
            bf16x8 bv = *(const bf16x8*)&Vlds[dt * 512 + lk * 128 + lr * 8];
            oacc[dt] = __builtin_amdgcn_mfma_f32_16x16x32_bf16(pa, bv, oacc[dt], 0, 0, 0);
        }
        __syncthreads();
    }

    #pragma unroll
    for (int j = 0; j < 4; ++j) {
        const float inv = 1.f / l_r[j];
        const int row = qrow + j;
        #pragma unroll
        for (int dt = 0; dt < 8; ++dt)
            ob[((size_t)row * NH + h) * HD + dt * 16 + lr] = f2bf(oacc[dt][j] * inv);
    }
}

extern "C" void kernel_launch(void* const* d_in, const int* in_sizes, int n_in,
                              void* d_out, int out_size, void* d_ws, size_t ws_size,
                              hipStream_t stream)
{
    const float* hs       = (const float*)d_in[0];
    const int*   pos      = (const int*)d_in[1];
    const int*   cu       = (const int*)d_in[2];
    const float* inv_freq = (const float*)d_in[3];
    const float* Wq       = (const float*)d_in[4];
    const float* bq       = (const float*)d_in[5];
    const float* Wk       = (const float*)d_in[6];
    const float* bk       = (const float*)d_in[7];
    const float* Wv       = (const float*)d_in[8];
    const float* bv       = (const float*)d_in[9];
    const float* Wo       = (const float*)d_in[10];
    float* out = (float*)d_out;

    unsigned short* hsb = (unsigned short*)d_ws;            // 8,388,608
    unsigned short* wqt = hsb + 8388608;                    // 4,194,304
    unsigned short* wkt = wqt + 4194304;                    //   524,288
    unsigned short* wvt = wkt + 524288;                     //   524,288
    unsigned short* wot = wvt + 524288;                     // 4,194,304
    unsigned short* qbb = wot + 4194304;                    // 8,388,608
    unsigned short* kbb = qbb + 8388608;                    // 1,048,576
    unsigned short* vbb = kbb + 1048576;                    // 1,048,576
    unsigned short* vtt = vbb + 1048576;                    // 1,048,576
    unsigned short* abb = vtt + 1048576;                    // 8,388,608

    conv_bf16<<<8192, 256, 0, stream>>>(hs, hsb, T_TOK * HIDDEN);
    transpose_w<<<dim3(HIDDEN / 32, HIDDEN / 32), 256, 0, stream>>>(Wq, wqt, HIDDEN, NH * HD);
    transpose_w<<<dim3((NKVH * HD) / 32, HIDDEN / 32), 256, 0, stream>>>(Wk, wkt, HIDDEN, NKVH * HD);
    transpose_w<<<dim3((NKVH * HD) / 32, HIDDEN / 32), 256, 0, stream>>>(Wv, wvt, HIDDEN, NKVH * HD);
    transpose_w<<<dim3(HIDDEN / 32, HIDDEN / 32), 256, 0, stream>>>(Wo, wot, NH * HD, HIDDEN);

    gemm_bt<true><<<dim3((NH * HD) / 128, T_TOK / 128), 256, 0, stream>>>(
        hsb, wqt, bq, qbb, NH * HD, HIDDEN);
    gemm_bt<true><<<dim3((NKVH * HD) / 128, T_TOK / 128), 256, 0, stream>>>(
        hsb, wkt, bk, kbb, NKVH * HD, HIDDEN);
    gemm_bt<true><<<dim3((NKVH * HD) / 128, T_TOK / 128), 256, 0, stream>>>(
        hsb, wvt, bv, vbb, NKVH * HD, HIDDEN);

    rope_kernel<<<dim3(T_TOK, NH + NKVH), dim3(64), 0, stream>>>(qbb, kbb, pos, inv_freq);
    transpose_v<<<dim3((NKVH * HD) / 64, T_TOK / 64), 256, 0, stream>>>(vbb, vtt);

    attn_mfma<<<dim3(T_TOK / 64, NH), 256, 0, stream>>>(qbb, kbb, vtt, cu, abb);

    gemm_bt<false><<<dim3(HIDDEN / 128, T_TOK / 128), 256, 0, stream>>>(
        abb, wot, nullptr, out, HIDDEN, NH * HD);
}

// Round 3
// 313.469 us; speedup vs baseline: 11.1147x; 1.3527x over previous
//
#include <hip/hip_runtime.h>
#include <math.h>

#define T_TOK 4096
#define HIDDEN 2048
#define NH 16
#define NKVH 2
#define HD 128
#define NSEG 8
#define QKV_N 2560   // 2048 q + 256 k + 256 v
#define ROW_Q 0
#define ROW_K 2048
#define ROW_V 2304

typedef __attribute__((ext_vector_type(8))) short bf16x8;
typedef __attribute__((ext_vector_type(4))) float f32x4;

__device__ __forceinline__ unsigned short f2bf(float f) {
    union { float f; unsigned u; } x; x.f = f;
    unsigned r = x.u + 0x7FFF + ((x.u >> 16) & 1);
    return (unsigned short)(r >> 16);
}
__device__ __forceinline__ float bf2f(unsigned short u) {
    union { unsigned u; float f; } x; x.u = ((unsigned)u) << 16;
    return x.f;
}
__device__ __forceinline__ void gload16(const void* g, void* l) {
    __builtin_amdgcn_global_load_lds(
        (const __attribute__((address_space(1))) unsigned int*)g,
        (__attribute__((address_space(3))) unsigned int*)l, 16, 0, 0);
}

// ---------- fp32 -> bf16 ----------
__global__ void conv_bf16(const float* __restrict__ in, unsigned short* __restrict__ out, int n)
{
    int i = (blockIdx.x * 256 + threadIdx.x) * 4;
    if (i + 3 < n) {
        float4 v = *(const float4*)&in[i];
        ushort4 o;
        o.x = f2bf(v.x); o.y = f2bf(v.y); o.z = f2bf(v.z); o.w = f2bf(v.w);
        *(ushort4*)&out[i] = o;
    }
}

// ---------- packed Wq|Wk|Wv transpose: WT[n][k], n in [0,2560) ----------
__global__ void transpose_wqkv(const float* __restrict__ Wq, const float* __restrict__ Wk,
                               const float* __restrict__ Wv, unsigned short* __restrict__ WT)
{
    __shared__ float tile[32][33];
    const int n0 = blockIdx.x * 32, k0 = blockIdx.y * 32;
    const float* src; int col0, stride;
    if (n0 < ROW_K)      { src = Wq; col0 = n0;         stride = NH * HD; }
    else if (n0 < ROW_V) { src = Wk; col0 = n0 - ROW_K; stride = NKVH * HD; }
    else                 { src = Wv; col0 = n0 - ROW_V; stride = NKVH * HD; }
    const int c = threadIdx.x & 31, r0 = threadIdx.x >> 5;
    #pragma unroll
    for (int r = r0; r < 32; r += 8)
        tile[r][c] = src[(size_t)(k0 + r) * stride + col0 + c];
    __syncthreads();
    #pragma unroll
    for (int r = r0; r < 32; r += 8)
        WT[(size_t)(n0 + r) * HIDDEN + k0 + c] = f2bf(tile[c][r]);
}

// ---------- W [K][N] fp32 -> WT [N][K] bf16 (for Wo) ----------
__global__ void transpose_w(const float* __restrict__ W, unsigned short* __restrict__ WT,
                            int K, int N)
{
    __shared__ float tile[32][33];
    const int k0 = blockIdx.y * 32, n0 = blockIdx.x * 32;
    const int c = threadIdx.x & 31, r0 = threadIdx.x >> 5;
    #pragma unroll
    for (int r = r0; r < 32; r += 8)
        tile[r][c] = W[(size_t)(k0 + r) * N + n0 + c];
    __syncthreads();
    #pragma unroll
    for (int r = r0; r < 32; r += 8)
        WT[(size_t)(n0 + r) * K + k0 + c] = f2bf(tile[c][r]);
}

__global__ void pack_bias(const float* __restrict__ bq, const float* __restrict__ bk,
                          const float* __restrict__ bv, float* __restrict__ o)
{
    int i = blockIdx.x * 256 + threadIdx.x;
    if (i < ROW_K) o[i] = bq[i];
    else if (i < ROW_V) o[i] = bk[i - ROW_K];
    else if (i < QKV_N) o[i] = bv[i - ROW_V];
}

// ---------- RoPE on packed qkv (q scaled by 1/sqrt(D)), fp32 math ----------
__global__ void rope_kernel(unsigned short* __restrict__ qkv, const int* __restrict__ pos,
                            const float* __restrict__ invf)
{
    const int tok = blockIdx.x * 4 + (threadIdx.x >> 6);
    const int f = threadIdx.x & 63;
    const float p = (float)pos[tok];
    const float ang = p * invf[f];
    const float c = cosf(ang), s = sinf(ang);
    const float SC = 0.08838834764831845f;
    unsigned short* row = qkv + (size_t)tok * QKV_N;
    #pragma unroll
    for (int h = 0; h < NH; ++h) {
        unsigned short* u = row + h * HD;
        const float x1 = bf2f(u[f]), x2 = bf2f(u[f + 64]);
        u[f]      = f2bf((x1 * c - x2 * s) * SC);
        u[f + 64] = f2bf((x2 * c + x1 * s) * SC);
    }
    #pragma unroll
    for (int h = 0; h < NKVH; ++h) {
        unsigned short* u = row + ROW_K + h * HD;
        const float x1 = bf2f(u[f]), x2 = bf2f(u[f + 64]);
        u[f]      = f2bf(x1 * c - x2 * s);
        u[f + 64] = f2bf(x2 * c + x1 * s);
    }
}

// ---------- bf16 MFMA GEMM, 2-phase prefetch: C = A * BT^T (+bias) ----------
// MODE 0: QKV (bf16 out stride QKV_N, bias, V cols written transposed to vt)
// MODE 1: O   (f32 out stride HIDDEN, no bias)
__device__ __forceinline__ void gemm_stage(const unsigned short* A, const unsigned short* BT,
                                           unsigned short* Al, unsigned short* Bl,
                                           int brow, int bcol, int K, int k0,
                                           int w, int lr, int lk)
{
    gload16(A + (size_t)(brow + w * 16 + lr) * K + k0 + lk * 8,        Al + w * 512);
    gload16(A + (size_t)(brow + (w + 4) * 16 + lr) * K + k0 + lk * 8,  Al + (w + 4) * 512);
    gload16(BT + (size_t)(bcol + w * 16 + lr) * K + k0 + lk * 8,       Bl + w * 512);
    gload16(BT + (size_t)(bcol + (w + 4) * 16 + lr) * K + k0 + lk * 8, Bl + (w + 4) * 512);
}

template<int MODE>
__global__ __launch_bounds__(256) void gemm_bt(const unsigned short* __restrict__ A,
                                               const unsigned short* __restrict__ BT,
                                               const float* __restrict__ bias,
                                               void* __restrict__ Cout,
                                               unsigned short* __restrict__ vt,
                                               int N, int K)
{
    __shared__ __align__(16) unsigned short Alds[2][4096];
    __shared__ __align__(16) unsigned short Blds[2][4096];
    const int tid = threadIdx.x;
    const int l = tid & 63, w = tid >> 6;
    const int wr = w >> 1, wc = w & 1;
    const int lr = l & 15, lk = l >> 4;
    const int brow = blockIdx.y * 128, bcol = blockIdx.x * 128;

    f32x4 acc[4][4];
    #pragma unroll
    for (int m = 0; m < 4; ++m)
        #pragma unroll
        for (int n = 0; n < 4; ++n)
            acc[m][n] = f32x4{0.f, 0.f, 0.f, 0.f};

    gemm_stage(A, BT, Alds[0], Blds[0], brow, bcol, K, 0, w, lr, lk);
    __syncthreads();

    const int nt = K >> 5;
    int buf = 0;
    for (int t = 0; t < nt; ++t) {
        if (t + 1 < nt)
            gemm_stage(A, BT, Alds[buf ^ 1], Blds[buf ^ 1], brow, bcol, K, (t + 1) * 32, w, lr, lk);
        bf16x8 av[4], bb[4];
        #pragma unroll
        for (int m = 0; m < 4; ++m)
            av[m] = *(const bf16x8*)&Alds[buf][(wr * 4 + m) * 512 + lk * 128 + lr * 8];
        #pragma unroll
        for (int n = 0; n < 4; ++n)
            bb[n] = *(const bf16x8*)&Blds[buf][(wc * 4 + n) * 512 + lk * 128 + lr * 8];
        #pragma unroll
        for (int m = 0; m < 4; ++m)
            #pragma unroll
            for (int n = 0; n < 4; ++n)
                acc[m][n] = __builtin_amdgcn_mfma_f32_16x16x32_bf16(av[m], bb[n], acc[m][n], 0, 0, 0);
        __syncthreads();
        buf ^= 1;
    }

    #pragma unroll
    for (int m = 0; m < 4; ++m) {
        const int row = brow + wr * 64 + m * 16 + lk * 4;
        #pragma unroll
        for (int n = 0; n < 4; ++n) {
            const int col = bcol + wc * 64 + n * 16 + lr;
            const float bbv = (MODE == 0) ? bias[col] : 0.f;
            if (MODE == 0 && col >= ROW_V) {
                ushort4 o;
                o.x = f2bf(acc[m][n][0] + bbv);
                o.y = f2bf(acc[m][n][1] + bbv);
                o.z = f2bf(acc[m][n][2] + bbv);
                o.w = f2bf(acc[m][n][3] + bbv);
                *(ushort4*)&vt[(size_t)(col - ROW_V) * T_TOK + row] = o;
            } else {
                #pragma unroll
                for (int j = 0; j < 4; ++j) {
                    const float vv = acc[m][n][j] + bbv;
                    if (MODE == 0)
                        ((unsigned short*)Cout)[(size_t)(row + j) * QKV_N + col] = f2bf(vv);
                    else
                        ((float*)Cout)[(size_t)(row + j) * HIDDEN + col] = vv;
                }
            }
        }
    }
}

// ---------- varlen causal GQA flash attention, bf16 MFMA, KB=64, 2-phase ----
__device__ __forceinline__ void attn_stage(const unsigned short* qkv, const unsigned short* vt,
                                           unsigned short* Kl, unsigned short* Vl,
                                           int s0, int kvh, int w, int lr, int lk)
{
    #pragma unroll
    for (int c = 0; c < 4; ++c)
        gload16(qkv + (size_t)(s0 + w * 16 + lr) * QKV_N + ROW_K + kvh * HD + c * 32 + lk * 8,
                Kl + w * 2048 + c * 512);
    #pragma unroll
    for (int c = 0; c < 4; ++c) {
        const int dt = w * 2 + (c >> 1), ks = c & 1;
        gload16(vt + (size_t)(kvh * HD + dt * 16 + lr) * T_TOK + s0 + ks * 32 + lk * 8,
                Vl + dt * 1024 + ks * 512);
    }
}

__global__ __launch_bounds__(256) void attn_mfma(const unsigned short* __restrict__ qkv,
                                                 const unsigned short* __restrict__ vt,
                                                 const int* __restrict__ cu,
                                                 unsigned short* __restrict__ ob)
{
    __shared__ __align__(16) unsigned short Klds[2][8192];  // [4 st][4 kb][4 lk][16 lr][8]
    __shared__ __align__(16) unsigned short Vlds[2][8192];  // [8 dt][2 ks][4 lk][16 lr][8]
    __shared__ __align__(16) unsigned short Plds[4][1152];  // per wave [16 q][72]

    const int tid = threadIdx.x;
    const int l = tid & 63, w = tid >> 6;
    const int lr = l & 15, lk = l >> 4;
    const int h = blockIdx.y, kvh = h >> 3;
    const int q0 = blockIdx.x * 64;

    // Q A-fragments in registers (pre-scaled by rope)
    bf16x8 aq[4];
    #pragma unroll
    for (int kk = 0; kk < 4; ++kk)
        aq[kk] = *(const bf16x8*)&qkv[(size_t)(q0 + w * 16 + lr) * QKV_N + h * HD + kk * 32 + lk * 8];

    const int qrow = q0 + w * 16 + lk * 4;
    int seg_lo[4];
    #pragma unroll
    for (int j = 0; j < 4; ++j) {
        int s = 0;
        #pragma unroll
        for (int x = 1; x < NSEG; ++x) s = (cu[x] <= qrow + j) ? cu[x] : s;
        seg_lo[j] = s;
    }
    int seg_last = 0, sb = 0;
    #pragma unroll
    for (int x = 1; x < NSEG; ++x) {
        seg_last = (cu[x] <= q0 + 63) ? cu[x] : seg_last;
        sb       = (cu[x] <= q0)      ? cu[x] : sb;
    }
    sb &= ~63;

    float m_r[4], l_r[4], al[4];
    #pragma unroll
    for (int j = 0; j < 4; ++j) { m_r[j] = -1e30f; l_r[j] = 0.f; }
    f32x4 oacc[8];
    #pragma unroll
    for (int d = 0; d < 8; ++d) oacc[d] = f32x4{0.f, 0.f, 0.f, 0.f};

    const int nt = ((q0 + 63 - sb) >> 6) + 1;
    attn_stage(qkv, vt, Klds[0], Vlds[0], sb, kvh, w, lr, lk);
    __syncthreads();

    int buf = 0;
    for (int t = 0; t < nt; ++t) {
        const int s0 = sb + t * 64;
        if (t + 1 < nt)
            attn_stage(qkv, vt, Klds[buf ^ 1], Vlds[buf ^ 1], s0 + 64, kvh, w, lr, lk);

        // S = Q K^T : 4 col-tiles x 4 k-steps
        f32x4 sacc[4];
        #pragma unroll
        for (int st = 0; st < 4; ++st) sacc[st] = f32x4{0.f, 0.f, 0.f, 0.f};
        #pragma unroll
        for (int kk = 0; kk < 4; ++kk)
            #pragma unroll
            for (int st = 0; st < 4; ++st) {
                bf16x8 bk = *(const bf16x8*)&Klds[buf][st * 2048 + kk * 512 + lk * 128 + lr * 8];
                sacc[st] = __builtin_amdgcn_mfma_f32_16x16x32_bf16(aq[kk], bk, sacc[st], 0, 0, 0);
            }

        const bool fast = (s0 >= seg_last) && (s0 + 63 <= q0);
        #pragma unroll
        for (int j = 0; j < 4; ++j) {
            float x[4];
            #pragma unroll
            for (int st = 0; st < 4; ++st) x[st] = sacc[st][j];
            if (!fast) {
                const int qg = qrow + j;
                #pragma unroll
                for (int st = 0; st < 4; ++st) {
                    const int sg = s0 + st * 16 + lr;
                    const bool vld = (sg >= seg_lo[j]) && (sg <= qg);
                    x[st] = vld ? x[st] : -3e38f;
                }
            }
            float mx = fmaxf(fmaxf(x[0], x[1]), fmaxf(x[2], x[3]));
            mx = fmaxf(mx, __shfl_xor(mx, 1));
            mx = fmaxf(mx, __shfl_xor(mx, 2));
            mx = fmaxf(mx, __shfl_xor(mx, 4));
            mx = fmaxf(mx, __shfl_xor(mx, 8));
            const float mn = fmaxf(m_r[j], mx);
            al[j] = __expf(m_r[j] - mn);
            float p[4], ps = 0.f;
            #pragma unroll
            for (int st = 0; st < 4; ++st) { p[st] = __expf(x[st] - mn); ps += p[st]; }
            ps += __shfl_xor(ps, 1);
            ps += __shfl_xor(ps, 2);
            ps += __shfl_xor(ps, 4);
            ps += __shfl_xor(ps, 8);
            l_r[j] = l_r[j] * al[j] + ps;
            m_r[j] = mn;
            #pragma unroll
            for (int st = 0; st < 4; ++st)
                Plds[w][(lk * 4 + j) * 72 + st * 16 + lr] = f2bf(p[st]);
        }
        #pragma unroll
        for (int dt = 0; dt < 8; ++dt) {
            oacc[dt][0] *= al[0]; oacc[dt][1] *= al[1];
            oacc[dt][2] *= al[2]; oacc[dt][3] *= al[3];
        }
        // PV (P is wave-local; compiler inserts lgkm wait)
        bf16x8 pa0 = *(const bf16x8*)&Plds[w][lr * 72 + lk * 8];
        bf16x8 pa1 = *(const bf16x8*)&Plds[w][lr * 72 + 32 + lk * 8];
        #pragma unroll
        for (int dt = 0; dt < 8; ++dt) {
            bf16x8 bv0 = *(const bf16x8*)&Vlds[buf][dt * 1024 + lk * 128 + lr * 8];
            oacc[dt] = __builtin_amdgcn_mfma_f32_16x16x32_bf16(pa0, bv0, oacc[dt], 0, 0, 0);
            bf16x8 bv1 = *(const bf16x8*)&Vlds[buf][dt * 1024 + 512 + lk * 128 + lr * 8];
            oacc[dt] = __builtin_amdgcn_mfma_f32_16x16x32_bf16(pa1, bv1, oacc[dt], 0, 0, 0);
        }
        __syncthreads();
        buf ^= 1;
    }

    #pragma unroll
    for (int j = 0; j < 4; ++j) {
        const float inv = 1.f / l_r[j];
        const int row = qrow + j;
        #pragma unroll
        for (int dt = 0; dt < 8; ++dt)
            ob[(size_t)row * (NH * HD) + h * HD + dt * 16 + lr] = f2bf(oacc[dt][j] * inv);
    }
}

extern "C" void kernel_launch(void* const* d_in, const int* in_sizes, int n_in,
                              void* d_out, int out_size, void* d_ws, size_t ws_size,
                              hipStream_t stream)
{
    const float* hs       = (const float*)d_in[0];
    const int*   pos      = (const int*)d_in[1];
    const int*   cu       = (const int*)d_in[2];
    const float* inv_freq = (const float*)d_in[3];
    const float* Wq       = (const float*)d_in[4];
    const float* bq       = (const float*)d_in[5];
    const float* Wk       = (const float*)d_in[6];
    const float* bk       = (const float*)d_in[7];
    const float* Wv       = (const float*)d_in[8];
    const float* bv       = (const float*)d_in[9];
    const float* Wo       = (const float*)d_in[10];
    float* out = (float*)d_out;

    unsigned short* hsb   = (unsigned short*)d_ws;          //  8,388,608
    unsigned short* wqkvT = hsb + 8388608;                  //  5,242,880
    unsigned short* wot   = wqkvT + 5242880;                //  4,194,304
    unsigned short* qkvb  = wot + 4194304;                  // 10,485,760
    unsigned short* vtb   = qkvb + 10485760;                //  1,048,576
    unsigned short* obb   = vtb + 1048576;                  //  8,388,608
    float* bqkv = (float*)(obb + 8388608);                  //  2,560 floats

    conv_bf16<<<8192, 256, 0, stream>>>(hs, hsb, T_TOK * HIDDEN);
    transpose_wqkv<<<dim3(QKV_N / 32, HIDDEN / 32), 256, 0, stream>>>(Wq, Wk, Wv, wqkvT);
    transpose_w<<<dim3(HIDDEN / 32, HIDDEN / 32), 256, 0, stream>>>(Wo, wot, NH * HD, HIDDEN);
    pack_bias<<<10, 256, 0, stream>>>(bq, bk, bv, bqkv);

    gemm_bt<0><<<dim3(QKV_N / 128, T_TOK / 128), 256, 0, stream>>>(
        hsb, wqkvT, bqkv, qkvb, vtb, QKV_N, HIDDEN);

    rope_kernel<<<dim3(T_TOK / 4), 256, 0, stream>>>(qkvb, pos, inv_freq);

    attn_mfma<<<dim3(T_TOK / 64, NH), 256, 0, stream>>>(qkvb, vtb, cu, obb);

    gemm_bt<1><<<dim3(HIDDEN / 128, T_TOK / 128), 256, 0, stream>>>(
        obb, wot, nullptr, out, nullptr, HIDDEN, NH * HD);
}

// Round 4
// 258.936 us; speedup vs baseline: 13.4556x; 1.2106x over previous
//
#include <hip/hip_runtime.h>
#include <math.h>

#define T_TOK 4096
#define HIDDEN 2048
#define NH 16
#define NKVH 2
#define HD 128
#define NSEG 8
#define QKV_N 2560   // 2048 q + 256 k + 256 v
#define ROW_Q 0
#define ROW_K 2048
#define ROW_V 2304

typedef __attribute__((ext_vector_type(8))) short bf16x8;
typedef __attribute__((ext_vector_type(4))) float f32x4;

__device__ __forceinline__ unsigned short f2bf(float f) {
    union { float f; unsigned u; } x; x.f = f;
    unsigned r = x.u + 0x7FFF + ((x.u >> 16) & 1);
    return (unsigned short)(r >> 16);
}
__device__ __forceinline__ float bf2f(unsigned short u) {
    union { unsigned u; float f; } x; x.u = ((unsigned)u) << 16;
    return x.f;
}
__device__ __forceinline__ void gload16(const void* g, void* l) {
    __builtin_amdgcn_global_load_lds(
        (const __attribute__((address_space(1))) unsigned int*)g,
        (__attribute__((address_space(3))) unsigned int*)l, 16, 0, 0);
}

// ---------- fp32 -> bf16 ----------
__global__ void conv_bf16(const float* __restrict__ in, unsigned short* __restrict__ out, int n)
{
    int i = (blockIdx.x * 256 + threadIdx.x) * 4;
    if (i + 3 < n) {
        float4 v = *(const float4*)&in[i];
        ushort4 o;
        o.x = f2bf(v.x); o.y = f2bf(v.y); o.z = f2bf(v.z); o.w = f2bf(v.w);
        *(ushort4*)&out[i] = o;
    }
}

// ---------- packed Wq|Wk|Wv transpose: WT[n][k], n in [0,2560) ----------
__global__ void transpose_wqkv(const float* __restrict__ Wq, const float* __restrict__ Wk,
                               const float* __restrict__ Wv, unsigned short* __restrict__ WT)
{
    __shared__ float tile[32][33];
    const int n0 = blockIdx.x * 32, k0 = blockIdx.y * 32;
    const float* src; int col0, stride;
    if (n0 < ROW_K)      { src = Wq; col0 = n0;         stride = NH * HD; }
    else if (n0 < ROW_V) { src = Wk; col0 = n0 - ROW_K; stride = NKVH * HD; }
    else                 { src = Wv; col0 = n0 - ROW_V; stride = NKVH * HD; }
    const int c = threadIdx.x & 31, r0 = threadIdx.x >> 5;
    #pragma unroll
    for (int r = r0; r < 32; r += 8)
        tile[r][c] = src[(size_t)(k0 + r) * stride + col0 + c];
    __syncthreads();
    #pragma unroll
    for (int r = r0; r < 32; r += 8)
        WT[(size_t)(n0 + r) * HIDDEN + k0 + c] = f2bf(tile[c][r]);
}

// ---------- W [K][N] fp32 -> WT [N][K] bf16 (for Wo) ----------
__global__ void transpose_w(const float* __restrict__ W, unsigned short* __restrict__ WT,
                            int K, int N)
{
    __shared__ float tile[32][33];
    const int k0 = blockIdx.y * 32, n0 = blockIdx.x * 32;
    const int c = threadIdx.x & 31, r0 = threadIdx.x >> 5;
    #pragma unroll
    for (int r = r0; r < 32; r += 8)
        tile[r][c] = W[(size_t)(k0 + r) * N + n0 + c];
    __syncthreads();
    #pragma unroll
    for (int r = r0; r < 32; r += 8)
        WT[(size_t)(n0 + r) * K + k0 + c] = f2bf(tile[c][r]);
}

__global__ void pack_bias(const float* __restrict__ bq, const float* __restrict__ bk,
                          const float* __restrict__ bv, float* __restrict__ o)
{
    int i = blockIdx.x * 256 + threadIdx.x;
    if (i < ROW_K) o[i] = bq[i];
    else if (i < ROW_V) o[i] = bk[i - ROW_K];
    else if (i < QKV_N) o[i] = bv[i - ROW_V];
}

// ---------- RoPE on packed qkv (q scaled by 1/sqrt(D)), fp32 math ----------
__global__ void rope_kernel(unsigned short* __restrict__ qkv, const int* __restrict__ pos,
                            const float* __restrict__ invf)
{
    const int tok = blockIdx.x * 4 + (threadIdx.x >> 6);
    const int f = threadIdx.x & 63;
    const float p = (float)pos[tok];
    const float ang = p * invf[f];
    const float c = cosf(ang), s = sinf(ang);
    const float SC = 0.08838834764831845f;
    unsigned short* row = qkv + (size_t)tok * QKV_N;
    #pragma unroll
    for (int h = 0; h < NH; ++h) {
        unsigned short* u = row + h * HD;
        const float x1 = bf2f(u[f]), x2 = bf2f(u[f + 64]);
        u[f]      = f2bf((x1 * c - x2 * s) * SC);
        u[f + 64] = f2bf((x2 * c + x1 * s) * SC);
    }
    #pragma unroll
    for (int h = 0; h < NKVH; ++h) {
        unsigned short* u = row + ROW_K + h * HD;
        const float x1 = bf2f(u[f]), x2 = bf2f(u[f + 64]);
        u[f]      = f2bf(x1 * c - x2 * s);
        u[f + 64] = f2bf(x2 * c + x1 * s);
    }
}

// ---------- bf16 MFMA GEMM, 2-phase prefetch: C = A * BT^T (+bias) ----------
__device__ __forceinline__ void gemm_stage(const unsigned short* A, const unsigned short* BT,
                                           unsigned short* Al, unsigned short* Bl,
                                           int brow, int bcol, int K, int k0,
                                           int w, int lr, int lk)
{
    gload16(A + (size_t)(brow + w * 16 + lr) * K + k0 + lk * 8,        Al + w * 512);
    gload16(A + (size_t)(brow + (w + 4) * 16 + lr) * K + k0 + lk * 8,  Al + (w + 4) * 512);
    gload16(BT + (size_t)(bcol + w * 16 + lr) * K + k0 + lk * 8,       Bl + w * 512);
    gload16(BT + (size_t)(bcol + (w + 4) * 16 + lr) * K + k0 + lk * 8, Bl + (w + 4) * 512);
}

template<int MODE>
__global__ __launch_bounds__(256) void gemm_bt(const unsigned short* __restrict__ A,
                                               const unsigned short* __restrict__ BT,
                                               const float* __restrict__ bias,
                                               void* __restrict__ Cout,
                                               unsigned short* __restrict__ vt,
                                               int N, int K)
{
    __shared__ __align__(16) unsigned short Alds[2][4096];
    __shared__ __align__(16) unsigned short Blds[2][4096];
    const int tid = threadIdx.x;
    const int l = tid & 63, w = tid >> 6;
    const int wr = w >> 1, wc = w & 1;
    const int lr = l & 15, lk = l >> 4;
    const int brow = blockIdx.y * 128, bcol = blockIdx.x * 128;

    f32x4 acc[4][4];
    #pragma unroll
    for (int m = 0; m < 4; ++m)
        #pragma unroll
        for (int n = 0; n < 4; ++n)
            acc[m][n] = f32x4{0.f, 0.f, 0.f, 0.f};

    gemm_stage(A, BT, Alds[0], Blds[0], brow, bcol, K, 0, w, lr, lk);
    __syncthreads();

    const int nt = K >> 5;
    int buf = 0;
    for (int t = 0; t < nt; ++t) {
        if (t + 1 < nt)
            gemm_stage(A, BT, Alds[buf ^ 1], Blds[buf ^ 1], brow, bcol, K, (t + 1) * 32, w, lr, lk);
        bf16x8 av[4], bb[4];
        #pragma unroll
        for (int m = 0; m < 4; ++m)
            av[m] = *(const bf16x8*)&Alds[buf][(wr * 4 + m) * 512 + lk * 128 + lr * 8];
        #pragma unroll
        for (int n = 0; n < 4; ++n)
            bb[n] = *(const bf16x8*)&Blds[buf][(wc * 4 + n) * 512 + lk * 128 + lr * 8];
        #pragma unroll
        for (int m = 0; m < 4; ++m)
            #pragma unroll
            for (int n = 0; n < 4; ++n)
                acc[m][n] = __builtin_amdgcn_mfma_f32_16x16x32_bf16(av[m], bb[n], acc[m][n], 0, 0, 0);
        __syncthreads();
        buf ^= 1;
    }

    #pragma unroll
    for (int m = 0; m < 4; ++m) {
        const int row = brow + wr * 64 + m * 16 + lk * 4;
        #pragma unroll
        for (int n = 0; n < 4; ++n) {
            const int col = bcol + wc * 64 + n * 16 + lr;
            const float bbv = (MODE == 0) ? bias[col] : 0.f;
            if (MODE == 0 && col >= ROW_V) {
                ushort4 o;
                o.x = f2bf(acc[m][n][0] + bbv);
                o.y = f2bf(acc[m][n][1] + bbv);
                o.z = f2bf(acc[m][n][2] + bbv);
                o.w = f2bf(acc[m][n][3] + bbv);
                *(ushort4*)&vt[(size_t)(col - ROW_V) * T_TOK + row] = o;
            } else {
                #pragma unroll
                for (int j = 0; j < 4; ++j) {
                    const float vv = acc[m][n][j] + bbv;
                    if (MODE == 0)
                        ((unsigned short*)Cout)[(size_t)(row + j) * QKV_N + col] = f2bf(vv);
                    else
                        ((float*)Cout)[(size_t)(row + j) * HIDDEN + col] = vv;
                }
            }
        }
    }
}

// ---------- varlen causal GQA flash attention ----------
// Swapped-operand MFMA: S^T = mfma(K,Q), O^T = mfma(V^T, P^T). P in registers.
// Block: 64 q-rows x 1 head, 4 waves (wave w = rows q0+w*16..+15, lane lr = 1 row).
// KB=32, K/V double-buffered, LDS = 32 KB -> ~4-5 blocks/CU.
__global__ __launch_bounds__(256) void attn_mfma(const unsigned short* __restrict__ qkv,
                                                 const unsigned short* __restrict__ vt,
                                                 const int* __restrict__ cu,
                                                 unsigned short* __restrict__ ob)
{
    __shared__ __align__(16) unsigned short Klds[2][4096]; // [st2][kk4][lk4][lr16][8]
    __shared__ __align__(16) unsigned short Vlds[2][4096]; // [dt8][lk4][lr16][8]

    const int tid = threadIdx.x;
    const int l = tid & 63, w = tid >> 6;
    const int lr = l & 15, lk = l >> 4;

    const int bid = blockIdx.x;
    const int h = bid >> 6;
    const int qb = (bid + 37 * (bid >> 6)) & 63;   // balance swizzle
    const int q0 = qb * 64;
    const int kvh = h >> 3;

    // Q B-fragments in registers (pre-scaled by 1/sqrt(D) in rope)
    bf16x8 aq[4];
    #pragma unroll
    for (int kk = 0; kk < 4; ++kk)
        aq[kk] = *(const bf16x8*)&qkv[(size_t)(q0 + w * 16 + lr) * QKV_N + h * HD + kk * 32 + lk * 8];

    const int qg = q0 + w * 16 + lr;     // this lane's q-row
    int seg_lo = 0, seg_last = 0, sb = 0;
    #pragma unroll
    for (int x = 1; x < NSEG; ++x) {
        const int cx = cu[x];
        seg_lo   = (cx <= qg)      ? cx : seg_lo;
        seg_last = (cx <= q0 + 63) ? cx : seg_last;
        sb       = (cx <= q0)      ? cx : sb;
    }
    sb &= ~31;

    // staging source pointers (cooperative, layout-indexed)
    const int lr_s = tid & 15, lk_s = (tid >> 4) & 3, w_s = tid >> 6;
    const unsigned short* kSrc0 = qkv + (size_t)(sb + lr_s) * QKV_N + ROW_K + kvh * HD + w_s * 32 + lk_s * 8;
    const unsigned short* kSrc1 = kSrc0 + (size_t)16 * QKV_N;
    const unsigned short* vSrc0 = vt + (size_t)(kvh * HD + w_s * 16 + lr_s) * T_TOK + sb + lk_s * 8;
    const unsigned short* vSrc1 = vSrc0 + (size_t)64 * T_TOK;

    float m_r = -1e30f, l_r = 0.f;
    f32x4 oacc[8];
    #pragma unroll
    for (int d = 0; d < 8; ++d) oacc[d] = f32x4{0.f, 0.f, 0.f, 0.f};

    const int nt = ((q0 + 63 - sb) >> 5) + 1;

    // prologue: stage tile 0
    gload16(kSrc0, &Klds[0][tid * 8]);
    gload16(kSrc1, &Klds[0][2048 + tid * 8]);
    gload16(vSrc0, &Vlds[0][tid * 8]);
    gload16(vSrc1, &Vlds[0][2048 + tid * 8]);
    __syncthreads();

    int buf = 0;
    for (int t = 0; t < nt; ++t) {
        const int s0 = sb + t * 32;
        kSrc0 += 32 * QKV_N; kSrc1 += 32 * QKV_N;
        vSrc0 += 32;         vSrc1 += 32;
        if (t + 1 < nt) {
            gload16(kSrc0, &Klds[buf ^ 1][tid * 8]);
            gload16(kSrc1, &Klds[buf ^ 1][2048 + tid * 8]);
            gload16(vSrc0, &Vlds[buf ^ 1][tid * 8]);
            gload16(vSrc1, &Vlds[buf ^ 1][2048 + tid * 8]);
        }

        // S^T = K Q^T : 2 s-tiles x 4 k-steps (A=K frag, B=Q frag)
        f32x4 sacc[2];
        sacc[0] = f32x4{0.f, 0.f, 0.f, 0.f};
        sacc[1] = f32x4{0.f, 0.f, 0.f, 0.f};
        #pragma unroll
        for (int kk = 0; kk < 4; ++kk) {
            bf16x8 ak0 = *(const bf16x8*)&Klds[buf][kk * 512 + lk * 128 + lr * 8];
            bf16x8 ak1 = *(const bf16x8*)&Klds[buf][2048 + kk * 512 + lk * 128 + lr * 8];
            sacc[0] = __builtin_amdgcn_mfma_f32_16x16x32_bf16(ak0, aq[kk], sacc[0], 0, 0, 0);
            sacc[1] = __builtin_amdgcn_mfma_f32_16x16x32_bf16(ak1, aq[kk], sacc[1], 0, 0, 0);
        }

        // per-lane: q-col = lr (one row), s = s0 + st*16 + lk*4 + jj
        float x[8];
        #pragma unroll
        for (int st = 0; st < 2; ++st)
            #pragma unroll
            for (int jj = 0; jj < 4; ++jj)
                x[st * 4 + jj] = sacc[st][jj];

        const bool fast = (s0 >= seg_last) && (s0 + 31 <= q0);
        if (!fast) {
            #pragma unroll
            for (int st = 0; st < 2; ++st)
                #pragma unroll
                for (int jj = 0; jj < 4; ++jj) {
                    const int sg = s0 + st * 16 + lk * 4 + jj;
                    const bool vld = (sg >= seg_lo) && (sg <= qg);
                    x[st * 4 + jj] = vld ? x[st * 4 + jj] : -3e38f;
                }
        }

        float mx = fmaxf(fmaxf(fmaxf(x[0], x[1]), fmaxf(x[2], x[3])),
                         fmaxf(fmaxf(x[4], x[5]), fmaxf(x[6], x[7])));
        mx = fmaxf(mx, __shfl_xor(mx, 16));
        mx = fmaxf(mx, __shfl_xor(mx, 32));
        const float mn = fmaxf(m_r, mx);
        const float al = __expf(m_r - mn);
        float p[8], ps = 0.f;
        #pragma unroll
        for (int i = 0; i < 8; ++i) { p[i] = __expf(x[i] - mn); ps += p[i]; }
        ps += __shfl_xor(ps, 16);
        ps += __shfl_xor(ps, 32);
        l_r = l_r * al + ps;
        m_r = mn;

        #pragma unroll
        for (int dt = 0; dt < 8; ++dt) {
            oacc[dt][0] *= al; oacc[dt][1] *= al;
            oacc[dt][2] *= al; oacc[dt][3] *= al;
        }

        // pack P to bf16 words: u[st][wd] = (bf(p[st*4+2wd+1])<<16) | bf(p[st*4+2wd])
        int u00 = ((int)f2bf(p[1]) << 16) | f2bf(p[0]);
        int u01 = ((int)f2bf(p[3]) << 16) | f2bf(p[2]);
        int u10 = ((int)f2bf(p[5]) << 16) | f2bf(p[4]);
        int u11 = ((int)f2bf(p[7]) << 16) | f2bf(p[6]);

        // redistribute to PV B-fragment: lane(lr,lk) needs P^T[s=lk*8+j][q=lr]
        const int srcA = (lk & 1) * 32 + lr;
        const int srcB = srcA + 16;
        const bool hi = (lk & 2) != 0;
        int a0 = __shfl(u00, srcA), b0 = __shfl(u10, srcA);
        int a1 = __shfl(u01, srcA), b1 = __shfl(u11, srcA);
        int a2 = __shfl(u00, srcB), b2 = __shfl(u10, srcB);
        int a3 = __shfl(u01, srcB), b3 = __shfl(u11, srcB);
        union { int wds[4]; bf16x8 v; } pf;
        pf.wds[0] = hi ? b0 : a0;
        pf.wds[1] = hi ? b1 : a1;
        pf.wds[2] = hi ? b2 : a2;
        pf.wds[3] = hi ? b3 : a3;

        // O^T += V^T P^T : A = V^T frag, B = P^T frag
        #pragma unroll
        for (int dt = 0; dt < 8; ++dt) {
            bf16x8 av = *(const bf16x8*)&Vlds[buf][dt * 512 + lk * 128 + lr * 8];
            oacc[dt] = __builtin_amdgcn_mfma_f32_16x16x32_bf16(av, pf.v, oacc[dt], 0, 0, 0);
        }
        __syncthreads();
        buf ^= 1;
    }

    // epilogue: lane holds O^T col q=qg, rows d = dt*16 + lk*4 + jj
    const float inv = 1.f / l_r;
    #pragma unroll
    for (int dt = 0; dt < 8; ++dt) {
        ushort4 o;
        o.x = f2bf(oacc[dt][0] * inv);
        o.y = f2bf(oacc[dt][1] * inv);
        o.z = f2bf(oacc[dt][2] * inv);
        o.w = f2bf(oacc[dt][3] * inv);
        *(ushort4*)&ob[(size_t)qg * (NH * HD) + h * HD + dt * 16 + lk * 4] = o;
    }
}

extern "C" void kernel_launch(void* const* d_in, const int* in_sizes, int n_in,
                              void* d_out, int out_size, void* d_ws, size_t ws_size,
                              hipStream_t stream)
{
    const float* hs       = (const float*)d_in[0];
    const int*   pos      = (const int*)d_in[1];
    const int*   cu       = (const int*)d_in[2];
    const float* inv_freq = (const float*)d_in[3];
    const float* Wq       = (const float*)d_in[4];
    const float* bq       = (const float*)d_in[5];
    const float* Wk       = (const float*)d_in[6];
    const float* bk       = (const float*)d_in[7];
    const float* Wv       = (const float*)d_in[8];
    const float* bv       = (const float*)d_in[9];
    const float* Wo       = (const float*)d_in[10];
    float* out = (float*)d_out;

    unsigned short* hsb   = (unsigned short*)d_ws;          //  8,388,608
    unsigned short* wqkvT = hsb + 8388608;                  //  5,242,880
    unsigned short* wot   = wqkvT + 5242880;                //  4,194,304
    unsigned short* qkvb  = wot + 4194304;                  // 10,485,760
    unsigned short* vtb   = qkvb + 10485760;                //  1,048,576
    unsigned short* obb   = vtb + 1048576;                  //  8,388,608
    float* bqkv = (float*)(obb + 8388608);                  //  2,560 floats

    conv_bf16<<<8192, 256, 0, stream>>>(hs, hsb, T_TOK * HIDDEN);
    transpose_wqkv<<<dim3(QKV_N / 32, HIDDEN / 32), 256, 0, stream>>>(Wq, Wk, Wv, wqkvT);
    transpose_w<<<dim3(HIDDEN / 32, HIDDEN / 32), 256, 0, stream>>>(Wo, wot, NH * HD, HIDDEN);
    pack_bias<<<10, 256, 0, stream>>>(bq, bk, bv, bqkv);

    gemm_bt<0><<<dim3(QKV_N / 128, T_TOK / 128), 256, 0, stream>>>(
        hsb, wqkvT, bqkv, qkvb, vtb, QKV_N, HIDDEN);

    rope_kernel<<<dim3(T_TOK / 4), 256, 0, stream>>>(qkvb, pos, inv_freq);

    attn_mfma<<<dim3(64 * NH), 256, 0, stream>>>(qkvb, vtb, cu, obb);

    gemm_bt<1><<<dim3(HIDDEN / 128, T_TOK / 128), 256, 0, stream>>>(
        obb, wot, nullptr, out, nullptr, HIDDEN, NH * HD);
}

// Round 5
// 219.646 us; speedup vs baseline: 15.8625x; 1.1789x over previous
//
#include <hip/hip_runtime.h>
#include <math.h>

#define T_TOK 4096
#define HIDDEN 2048
#define NH 16
#define NKVH 2
#define HD 128
#define NSEG 8
#define QKV_N 2560   // 2048 q + 256 k + 256 v
#define ROW_Q 0
#define ROW_K 2048
#define ROW_V 2304

typedef __attribute__((ext_vector_type(8))) short bf16x8;
typedef __attribute__((ext_vector_type(4))) float f32x4;

__device__ __forceinline__ unsigned short f2bf(float f) {
    union { float f; unsigned u; } x; x.f = f;
    unsigned r = x.u + 0x7FFF + ((x.u >> 16) & 1);
    return (unsigned short)(r >> 16);
}
__device__ __forceinline__ float bf2f(unsigned short u) {
    union { unsigned u; float f; } x; x.u = ((unsigned)u) << 16;
    return x.f;
}
__device__ __forceinline__ void gload16(const void* g, void* l) {
    __builtin_amdgcn_global_load_lds(
        (const __attribute__((address_space(1))) unsigned int*)g,
        (__attribute__((address_space(3))) unsigned int*)l, 16, 0, 0);
}

#define SB0() __builtin_amdgcn_sched_barrier(0)
#define BAR() do { SB0(); asm volatile("" ::: "memory"); __builtin_amdgcn_s_barrier(); \
                   asm volatile("" ::: "memory"); SB0(); } while (0)

// ---------- fp32 -> bf16 ----------
__global__ void conv_bf16(const float* __restrict__ in, unsigned short* __restrict__ out, int n)
{
    int i = (blockIdx.x * 256 + threadIdx.x) * 4;
    if (i + 3 < n) {
        float4 v = *(const float4*)&in[i];
        ushort4 o;
        o.x = f2bf(v.x); o.y = f2bf(v.y); o.z = f2bf(v.z); o.w = f2bf(v.w);
        *(ushort4*)&out[i] = o;
    }
}

// ---------- packed Wq|Wk|Wv transpose: WT[n][k], n in [0,2560) ----------
__global__ void transpose_wqkv(const float* __restrict__ Wq, const float* __restrict__ Wk,
                               const float* __restrict__ Wv, unsigned short* __restrict__ WT)
{
    __shared__ float tile[32][33];
    const int n0 = blockIdx.x * 32, k0 = blockIdx.y * 32;
    const float* src; int col0, stride;
    if (n0 < ROW_K)      { src = Wq; col0 = n0;         stride = NH * HD; }
    else if (n0 < ROW_V) { src = Wk; col0 = n0 - ROW_K; stride = NKVH * HD; }
    else                 { src = Wv; col0 = n0 - ROW_V; stride = NKVH * HD; }
    const int c = threadIdx.x & 31, r0 = threadIdx.x >> 5;
    #pragma unroll
    for (int r = r0; r < 32; r += 8)
        tile[r][c] = src[(size_t)(k0 + r) * stride + col0 + c];
    __syncthreads();
    #pragma unroll
    for (int r = r0; r < 32; r += 8)
        WT[(size_t)(n0 + r) * HIDDEN + k0 + c] = f2bf(tile[c][r]);
}

// ---------- W [K][N] fp32 -> WT [N][K] bf16 (for Wo) ----------
__global__ void transpose_w(const float* __restrict__ W, unsigned short* __restrict__ WT,
                            int K, int N)
{
    __shared__ float tile[32][33];
    const int k0 = blockIdx.y * 32, n0 = blockIdx.x * 32;
    const int c = threadIdx.x & 31, r0 = threadIdx.x >> 5;
    #pragma unroll
    for (int r = r0; r < 32; r += 8)
        tile[r][c] = W[(size_t)(k0 + r) * N + n0 + c];
    __syncthreads();
    #pragma unroll
    for (int r = r0; r < 32; r += 8)
        WT[(size_t)(n0 + r) * K + k0 + c] = f2bf(tile[c][r]);
}

__global__ void pack_bias(const float* __restrict__ bq, const float* __restrict__ bk,
                          const float* __restrict__ bv, float* __restrict__ o)
{
    int i = blockIdx.x * 256 + threadIdx.x;
    if (i < ROW_K) o[i] = bq[i];
    else if (i < ROW_V) o[i] = bk[i - ROW_K];
    else if (i < QKV_N) o[i] = bv[i - ROW_V];
}

// ---------- RoPE on packed qkv (q scaled by 1/sqrt(D)), fp32 math ----------
__global__ void rope_kernel(unsigned short* __restrict__ qkv, const int* __restrict__ pos,
                            const float* __restrict__ invf)
{
    const int tok = blockIdx.x * 4 + (threadIdx.x >> 6);
    const int f = threadIdx.x & 63;
    const float p = (float)pos[tok];
    const float ang = p * invf[f];
    const float c = cosf(ang), s = sinf(ang);
    const float SC = 0.08838834764831845f;
    unsigned short* row = qkv + (size_t)tok * QKV_N;
    #pragma unroll
    for (int h = 0; h < NH; ++h) {
        unsigned short* u = row + h * HD;
        const float x1 = bf2f(u[f]), x2 = bf2f(u[f + 64]);
        u[f]      = f2bf((x1 * c - x2 * s) * SC);
        u[f + 64] = f2bf((x2 * c + x1 * s) * SC);
    }
    #pragma unroll
    for (int h = 0; h < NKVH; ++h) {
        unsigned short* u = row + ROW_K + h * HD;
        const float x1 = bf2f(u[f]), x2 = bf2f(u[f + 64]);
        u[f]      = f2bf(x1 * c - x2 * s);
        u[f + 64] = f2bf(x2 * c + x1 * s);
    }
}

// ============ 8-phase 256xBN MFMA GEMM (T3+T4+T5, T1) ============
// C[M][N] = A[M][K] * BT[N][K]^T (+bias). BM=256, BK=64, 8 waves (2m x 4n).
// MODE 0: BN=256, bf16 out stride QKV_N, bias, V cols written transposed to vt
// MODE 1: BN=128, f32 out stride HIDDEN, no bias
// LDS per operand buf: [2 half][8 subtile][8 kblk][16 row][8 k] (linear, conflict-free)
template<int MODE>
__global__ __launch_bounds__(512, 2) void gemm8(const unsigned short* __restrict__ A,
                                                const unsigned short* __restrict__ BT,
                                                const float* __restrict__ bias,
                                                void* __restrict__ Cout,
                                                unsigned short* __restrict__ vt,
                                                int N, int K)
{
    constexpr int BN    = (MODE == 0) ? 256 : 128;
    constexpr int NPH   = (MODE == 0) ? 2 : 1;        // n-subtiles per nh half per wave
    constexpr int BHALF = (MODE == 0) ? 16384 : 8192; // bytes per B half-tile
    constexpr int ABUF  = 32768;
    constexpr int BBUF  = 2 * BHALF;
    constexpr int BOFF  = 2 * ABUF;
    __shared__ __align__(16) unsigned char lds[BOFF + 2 * BBUF];

    const int tid = threadIdx.x, lane = tid & 63, w = tid >> 6;
    const int wm = w >> 2, wn = w & 3;
    const int lr = lane & 15, lk = lane >> 4;

    const int NTN = N / BN;
    const int cpx = gridDim.x >> 3;
    const int bid = blockIdx.x;
    const int wg = (bid & 7) * cpx + (bid >> 3);      // XCD swizzle (nwg % 8 == 0)
    const int brow = (wg / NTN) * 256, bcol = (wg % NTN) * BN;

    // per-thread staging constants (rt=w, kb=i*4+lk, lrow=lr)
    const size_t aRow = (size_t)(brow + w * 16 + lr) * K + lk * 8;
    size_t bRow;
    if constexpr (MODE == 0) bRow = (size_t)(bcol + w * 16 + lr) * K + lk * 8;
    else                     bRow = (size_t)(bcol + (w >> 1) * 16 + lr) * K + ((w & 1) * 4 + lk) * 8;
    const int dstA = w * 2048 + lane * 16;
    const int dstB = (MODE == 0) ? dstA : (w * 1024 + lane * 16);

    auto stA = [&](int kt, int h, int b) {
        const unsigned short* s = A + aRow + (size_t)h * 128 * K + kt * 64;
        unsigned char* d = lds + b * ABUF + h * 16384 + dstA;
        gload16(s, d);
        gload16(s + 32, d + 1024);
    };
    auto stB = [&](int kt, int h, int b) {
        const unsigned short* s = BT + bRow + (size_t)h * (BN / 2) * K + kt * 64;
        unsigned char* d = lds + BOFF + b * BBUF + h * BHALF + dstB;
        gload16(s, d);
        if constexpr (MODE == 0) gload16(s + 32, d + 1024);
    };

    const int fragOff = lk * 256 + lr * 16;
    auto ldA = [&](int b, int mh, int m, int kk) -> bf16x8 {
        return *(const bf16x8*)(lds + b * ABUF + mh * 16384 + (wm * 4 + m) * 2048
                                + kk * 1024 + fragOff);
    };
    auto ldB = [&](int b, int nh, int n, int kk) -> bf16x8 {
        const int sub = (MODE == 0) ? (wn * 2 + n) : wn;
        return *(const bf16x8*)(lds + BOFF + b * BBUF + nh * BHALF + sub * 2048
                                + kk * 1024 + fragOff);
    };

    f32x4 acc[8][2 * NPH];
    #pragma unroll
    for (int i = 0; i < 8; ++i)
        #pragma unroll
        for (int j = 0; j < 2 * NPH; ++j)
            acc[i][j] = f32x4{0.f, 0.f, 0.f, 0.f};

    const int NT = K >> 6;

    // prologue: K0 fully (4 half-tiles) + {A0,B0,B1} of K1
    stA(0, 0, 0); stA(0, 1, 0); stB(0, 0, 0); stB(0, 1, 0);
    stA(1, 0, 1); stB(1, 0, 1); stB(1, 1, 1);
    if constexpr (MODE == 0) asm volatile("s_waitcnt vmcnt(6)" ::: "memory");
    else                     asm volatile("s_waitcnt vmcnt(4)" ::: "memory");
    BAR();

    for (int kt = 0; kt < NT; ++kt) {
        const int b = kt & 1;
        bf16x8 af[4][2], bfr[2][NPH][2];

        // ---- ph0: read A-h0 (8) + B-h0; stage A1(kt+1) -> buf b^1
        #pragma unroll
        for (int m = 0; m < 4; ++m) {
            af[m][0] = ldA(b, 0, m, 0);
            af[m][1] = ldA(b, 0, m, 1);
        }
        #pragma unroll
        for (int n = 0; n < NPH; ++n) {
            bfr[0][n][0] = ldB(b, 0, n, 0);
            bfr[0][n][1] = ldB(b, 0, n, 1);
        }
        if (kt + 1 < NT) stA(kt + 1, 1, b ^ 1);
        BAR();
        __builtin_amdgcn_s_setprio(1);
        #pragma unroll
        for (int m = 0; m < 4; ++m)
            #pragma unroll
            for (int n = 0; n < NPH; ++n)
                #pragma unroll
                for (int kk = 0; kk < 2; ++kk)
                    acc[m][n] = __builtin_amdgcn_mfma_f32_16x16x32_bf16(
                        af[m][kk], bfr[0][n][kk], acc[m][n], 0, 0, 0);
        __builtin_amdgcn_s_setprio(0);
        BAR();

        // ---- ph1: read B-h1; stage A0(kt+2) -> buf b
        #pragma unroll
        for (int n = 0; n < NPH; ++n) {
            bfr[1][n][0] = ldB(b, 1, n, 0);
            bfr[1][n][1] = ldB(b, 1, n, 1);
        }
        if (kt + 2 < NT) stA(kt + 2, 0, b);
        BAR();
        __builtin_amdgcn_s_setprio(1);
        #pragma unroll
        for (int m = 0; m < 4; ++m)
            #pragma unroll
            for (int n = 0; n < NPH; ++n)
                #pragma unroll
                for (int kk = 0; kk < 2; ++kk)
                    acc[m][NPH + n] = __builtin_amdgcn_mfma_f32_16x16x32_bf16(
                        af[m][kk], bfr[1][n][kk], acc[m][NPH + n], 0, 0, 0);
        __builtin_amdgcn_s_setprio(0);
        BAR();

        // ---- ph2: read A-h1 (8); stage B0(kt+2) -> buf b
        #pragma unroll
        for (int m = 0; m < 4; ++m) {
            af[m][0] = ldA(b, 1, m, 0);
            af[m][1] = ldA(b, 1, m, 1);
        }
        if (kt + 2 < NT) stB(kt + 2, 0, b);
        BAR();
        __builtin_amdgcn_s_setprio(1);
        #pragma unroll
        for (int m = 0; m < 4; ++m)
            #pragma unroll
            for (int n = 0; n < NPH; ++n)
                #pragma unroll
                for (int kk = 0; kk < 2; ++kk)
                    acc[4 + m][n] = __builtin_amdgcn_mfma_f32_16x16x32_bf16(
                        af[m][kk], bfr[0][n][kk], acc[4 + m][n], 0, 0, 0);
        __builtin_amdgcn_s_setprio(0);
        BAR();

        // ---- ph3: stage B1(kt+2) -> buf b; counted vmcnt (once per K-tile)
        if (kt + 2 < NT) stB(kt + 2, 1, b);
        if (kt < NT - 2) {
            if constexpr (MODE == 0) asm volatile("s_waitcnt vmcnt(6)" ::: "memory");
            else                     asm volatile("s_waitcnt vmcnt(4)" ::: "memory");
        } else {
            asm volatile("s_waitcnt vmcnt(0)" ::: "memory");
        }
        BAR();
        __builtin_amdgcn_s_setprio(1);
        #pragma unroll
        for (int m = 0; m < 4; ++m)
            #pragma unroll
            for (int n = 0; n < NPH; ++n)
                #pragma unroll
                for (int kk = 0; kk < 2; ++kk)
                    acc[4 + m][NPH + n] = __builtin_amdgcn_mfma_f32_16x16x32_bf16(
                        af[m][kk], bfr[1][n][kk], acc[4 + m][NPH + n], 0, 0, 0);
        __builtin_amdgcn_s_setprio(0);
        BAR();
    }

    // epilogue
    #pragma unroll
    for (int ms = 0; ms < 8; ++ms) {
        const int row = brow + (ms >> 2) * 128 + wm * 64 + (ms & 3) * 16 + lk * 4;
        #pragma unroll
        for (int ns = 0; ns < 2 * NPH; ++ns) {
            int col;
            if constexpr (MODE == 0)
                col = bcol + (ns >> 1) * 128 + wn * 32 + (ns & 1) * 16 + lr;
            else
                col = bcol + ns * 64 + wn * 16 + lr;
            const float bbv = (MODE == 0) ? bias[col] : 0.f;
            if (MODE == 0 && col >= ROW_V) {
                ushort4 o;
                o.x = f2bf(acc[ms][ns][0] + bbv);
                o.y = f2bf(acc[ms][ns][1] + bbv);
                o.z = f2bf(acc[ms][ns][2] + bbv);
                o.w = f2bf(acc[ms][ns][3] + bbv);
                *(ushort4*)&vt[(size_t)(col - ROW_V) * T_TOK + row] = o;
            } else {
                #pragma unroll
                for (int j = 0; j < 4; ++j) {
                    const float vv = acc[ms][ns][j] + bbv;
                    if (MODE == 0)
                        ((unsigned short*)Cout)[(size_t)(row + j) * QKV_N + col] = f2bf(vv);
                    else
                        ((float*)Cout)[(size_t)(row + j) * HIDDEN + col] = vv;
                }
            }
        }
    }
}

// ---------- varlen causal GQA flash attention ----------
// Swapped-operand MFMA: S^T = mfma(K,Q), O^T = mfma(V^T, P^T). P in registers.
__global__ __launch_bounds__(256) void attn_mfma(const unsigned short* __restrict__ qkv,
                                                 const unsigned short* __restrict__ vt,
                                                 const int* __restrict__ cu,
                                                 unsigned short* __restrict__ ob)
{
    __shared__ __align__(16) unsigned short Klds[2][4096]; // [st2][kk4][lk4][lr16][8]
    __shared__ __align__(16) unsigned short Vlds[2][4096]; // [dt8][lk4][lr16][8]

    const int tid = threadIdx.x;
    const int l = tid & 63, w = tid >> 6;
    const int lr = l & 15, lk = l >> 4;

    const int bid = blockIdx.x;
    const int h = bid >> 6;
    const int qb = (bid + 37 * (bid >> 6)) & 63;   // balance swizzle
    const int q0 = qb * 64;
    const int kvh = h >> 3;

    bf16x8 aq[4];
    #pragma unroll
    for (int kk = 0; kk < 4; ++kk)
        aq[kk] = *(const bf16x8*)&qkv[(size_t)(q0 + w * 16 + lr) * QKV_N + h * HD + kk * 32 + lk * 8];

    const int qg = q0 + w * 16 + lr;
    int seg_lo = 0, seg_last = 0, sb = 0;
    #pragma unroll
    for (int x = 1; x < NSEG; ++x) {
        const int cx = cu[x];
        seg_lo   = (cx <= qg)      ? cx : seg_lo;
        seg_last = (cx <= q0 + 63) ? cx : seg_last;
        sb       = (cx <= q0)      ? cx : sb;
    }
    sb &= ~31;

    const int lr_s = tid & 15, lk_s = (tid >> 4) & 3, w_s = tid >> 6;
    const unsigned short* kSrc0 = qkv + (size_t)(sb + lr_s) * QKV_N + ROW_K + kvh * HD + w_s * 32 + lk_s * 8;
    const unsigned short* kSrc1 = kSrc0 + (size_t)16 * QKV_N;
    const unsigned short* vSrc0 = vt + (size_t)(kvh * HD + w_s * 16 + lr_s) * T_TOK + sb + lk_s * 8;
    const unsigned short* vSrc1 = vSrc0 + (size_t)64 * T_TOK;

    float m_r = -1e30f, l_r = 0.f;
    f32x4 oacc[8];
    #pragma unroll
    for (int d = 0; d < 8; ++d) oacc[d] = f32x4{0.f, 0.f, 0.f, 0.f};

    const int nt = ((q0 + 63 - sb) >> 5) + 1;

    gload16(kSrc0, &Klds[0][tid * 8]);
    gload16(kSrc1, &Klds[0][2048 + tid * 8]);
    gload16(vSrc0, &Vlds[0][tid * 8]);
    gload16(vSrc1, &Vlds[0][2048 + tid * 8]);
    __syncthreads();

    int buf = 0;
    for (int t = 0; t < nt; ++t) {
        const int s0 = sb + t * 32;
        kSrc0 += 32 * QKV_N; kSrc1 += 32 * QKV_N;
        vSrc0 += 32;         vSrc1 += 32;
        if (t + 1 < nt) {
            gload16(kSrc0, &Klds[buf ^ 1][tid * 8]);
            gload16(kSrc1, &Klds[buf ^ 1][2048 + tid * 8]);
            gload16(vSrc0, &Vlds[buf ^ 1][tid * 8]);
            gload16(vSrc1, &Vlds[buf ^ 1][2048 + tid * 8]);
        }

        f32x4 sacc[2];
        sacc[0] = f32x4{0.f, 0.f, 0.f, 0.f};
        sacc[1] = f32x4{0.f, 0.f, 0.f, 0.f};
        #pragma unroll
        for (int kk = 0; kk < 4; ++kk) {
            bf16x8 ak0 = *(const bf16x8*)&Klds[buf][kk * 512 + lk * 128 + lr * 8];
            bf16x8 ak1 = *(const bf16x8*)&Klds[buf][2048 + kk * 512 + lk * 128 + lr * 8];
            sacc[0] = __builtin_amdgcn_mfma_f32_16x16x32_bf16(ak0, aq[kk], sacc[0], 0, 0, 0);
            sacc[1] = __builtin_amdgcn_mfma_f32_16x16x32_bf16(ak1, aq[kk], sacc[1], 0, 0, 0);
        }

        float x[8];
        #pragma unroll
        for (int st = 0; st < 2; ++st)
            #pragma unroll
            for (int jj = 0; jj < 4; ++jj)
                x[st * 4 + jj] = sacc[st][jj];

        const bool fast = (s0 >= seg_last) && (s0 + 31 <= q0);
        if (!fast) {
            #pragma unroll
            for (int st = 0; st < 2; ++st)
                #pragma unroll
                for (int jj = 0; jj < 4; ++jj) {
                    const int sg = s0 + st * 16 + lk * 4 + jj;
                    const bool vld = (sg >= seg_lo) && (sg <= qg);
                    x[st * 4 + jj] = vld ? x[st * 4 + jj] : -3e38f;
                }
        }

        float mx = fmaxf(fmaxf(fmaxf(x[0], x[1]), fmaxf(x[2], x[3])),
                         fmaxf(fmaxf(x[4], x[5]), fmaxf(x[6], x[7])));
        mx = fmaxf(mx, __shfl_xor(mx, 16));
        mx = fmaxf(mx, __shfl_xor(mx, 32));
        const float mn = fmaxf(m_r, mx);
        const float al = __expf(m_r - mn);
        float p[8], ps = 0.f;
        #pragma unroll
        for (int i = 0; i < 8; ++i) { p[i] = __expf(x[i] - mn); ps += p[i]; }
        ps += __shfl_xor(ps, 16);
        ps += __shfl_xor(ps, 32);
        l_r = l_r * al + ps;
        m_r = mn;

        #pragma unroll
        for (int dt = 0; dt < 8; ++dt) {
            oacc[dt][0] *= al; oacc[dt][1] *= al;
            oacc[dt][2] *= al; oacc[dt][3] *= al;
        }

        int u00 = ((int)f2bf(p[1]) << 16) | f2bf(p[0]);
        int u01 = ((int)f2bf(p[3]) << 16) | f2bf(p[2]);
        int u10 = ((int)f2bf(p[5]) << 16) | f2bf(p[4]);
        int u11 = ((int)f2bf(p[7]) << 16) | f2bf(p[6]);

        const int srcA = (lk & 1) * 32 + lr;
        const int srcB = srcA + 16;
        const bool hi = (lk & 2) != 0;
        int a0 = __shfl(u00, srcA), b0 = __shfl(u10, srcA);
        int a1 = __shfl(u01, srcA), b1 = __shfl(u11, srcA);
        int a2 = __shfl(u00, srcB), b2 = __shfl(u10, srcB);
        int a3 = __shfl(u01, srcB), b3 = __shfl(u11, srcB);
        union { int wds[4]; bf16x8 v; } pf;
        pf.wds[0] = hi ? b0 : a0;
        pf.wds[1] = hi ? b1 : a1;
        pf.wds[2] = hi ? b2 : a2;
        pf.wds[3] = hi ? b3 : a3;

        #pragma unroll
        for (int dt = 0; dt < 8; ++dt) {
            bf16x8 av = *(const bf16x8*)&Vlds[buf][dt * 512 + lk * 128 + lr * 8];
            oacc[dt] = __builtin_amdgcn_mfma_f32_16x16x32_bf16(av, pf.v, oacc[dt], 0, 0, 0);
        }
        __syncthreads();
        buf ^= 1;
    }

    const float inv = 1.f / l_r;
    #pragma unroll
    for (int dt = 0; dt < 8; ++dt) {
        ushort4 o;
        o.x = f2bf(oacc[dt][0] * inv);
        o.y = f2bf(oacc[dt][1] * inv);
        o.z = f2bf(oacc[dt][2] * inv);
        o.w = f2bf(oacc[dt][3] * inv);
        *(ushort4*)&ob[(size_t)qg * (NH * HD) + h * HD + dt * 16 + lk * 4] = o;
    }
}

extern "C" void kernel_launch(void* const* d_in, const int* in_sizes, int n_in,
                              void* d_out, int out_size, void* d_ws, size_t ws_size,
                              hipStream_t stream)
{
    const float* hs       = (const float*)d_in[0];
    const int*   pos      = (const int*)d_in[1];
    const int*   cu       = (const int*)d_in[2];
    const float* inv_freq = (const float*)d_in[3];
    const float* Wq       = (const float*)d_in[4];
    const float* bq       = (const float*)d_in[5];
    const float* Wk       = (const float*)d_in[6];
    const float* bk       = (const float*)d_in[7];
    const float* Wv       = (const float*)d_in[8];
    const float* bv       = (const float*)d_in[9];
    const float* Wo       = (const float*)d_in[10];
    float* out = (float*)d_out;

    unsigned short* hsb   = (unsigned short*)d_ws;          //  8,388,608
    unsigned short* wqkvT = hsb + 8388608;                  //  5,242,880
    unsigned short* wot   = wqkvT + 5242880;                //  4,194,304
    unsigned short* qkvb  = wot + 4194304;                  // 10,485,760
    unsigned short* vtb   = qkvb + 10485760;                //  1,048,576
    unsigned short* obb   = vtb + 1048576;                  //  8,388,608
    float* bqkv = (float*)(obb + 8388608);                  //  2,560 floats

    conv_bf16<<<8192, 256, 0, stream>>>(hs, hsb, T_TOK * HIDDEN);
    transpose_wqkv<<<dim3(QKV_N / 32, HIDDEN / 32), 256, 0, stream>>>(Wq, Wk, Wv, wqkvT);
    transpose_w<<<dim3(HIDDEN / 32, HIDDEN / 32), 256, 0, stream>>>(Wo, wot, NH * HD, HIDDEN);
    pack_bias<<<10, 256, 0, stream>>>(bq, bk, bv, bqkv);

    gemm8<0><<<dim3((T_TOK / 256) * (QKV_N / 256)), 512, 0, stream>>>(
        hsb, wqkvT, bqkv, qkvb, vtb, QKV_N, HIDDEN);

    rope_kernel<<<dim3(T_TOK / 4), 256, 0, stream>>>(qkvb, pos, inv_freq);

    attn_mfma<<<dim3(64 * NH), 256, 0, stream>>>(qkvb, vtb, cu, obb);

    gemm8<1><<<dim3((T_TOK / 256) * (HIDDEN / 128)), 512, 0, stream>>>(
        obb, wot, nullptr, out, nullptr, HIDDEN, NH * HD);
}

// Round 6
// 219.131 us; speedup vs baseline: 15.8998x; 1.0024x over previous
//
#include <hip/hip_runtime.h>
#include <math.h>

#define T_TOK 4096
#define HIDDEN 2048
#define NH 16
#define NKVH 2
#define HD 128
#define NSEG 8
#define QKV_N 2560   // 2048 q + 256 k + 256 v
#define ROW_Q 0
#define ROW_K 2048
#define ROW_V 2304

typedef __attribute__((ext_vector_type(8))) short bf16x8;
typedef __attribute__((ext_vector_type(4))) float f32x4;

__device__ __forceinline__ unsigned short f2bf(float f) {
    union { float f; unsigned u; } x; x.f = f;
    unsigned r = x.u + 0x7FFF + ((x.u >> 16) & 1);
    return (unsigned short)(r >> 16);
}
__device__ __forceinline__ float bf2f(unsigned short u) {
    union { unsigned u; float f; } x; x.u = ((unsigned)u) << 16;
    return x.f;
}
__device__ __forceinline__ void gload16(const void* g, void* l) {
    __builtin_amdgcn_global_load_lds(
        (const __attribute__((address_space(1))) unsigned int*)g,
        (__attribute__((address_space(3))) unsigned int*)l, 16, 0, 0);
}

// Raw barrier: memory clobber orders LDS/VMEM ops across it, but register-only
// MFMA clusters may interleave with neighboring phases (m196's lever).
// NO sched_barrier(0), NO implicit vmcnt drain (unlike __syncthreads).
#define BAR() asm volatile("s_barrier" ::: "memory")

// ---------- fp32 -> bf16 ----------
__global__ void conv_bf16(const float* __restrict__ in, unsigned short* __restrict__ out, int n)
{
    int i = (blockIdx.x * 256 + threadIdx.x) * 4;
    if (i + 3 < n) {
        float4 v = *(const float4*)&in[i];
        ushort4 o;
        o.x = f2bf(v.x); o.y = f2bf(v.y); o.z = f2bf(v.z); o.w = f2bf(v.w);
        *(ushort4*)&out[i] = o;
    }
}

// ---------- packed Wq|Wk|Wv transpose: WT[n][k], n in [0,2560) ----------
__global__ void transpose_wqkv(const float* __restrict__ Wq, const float* __restrict__ Wk,
                               const float* __restrict__ Wv, unsigned short* __restrict__ WT)
{
    __shared__ float tile[32][33];
    const int n0 = blockIdx.x * 32, k0 = blockIdx.y * 32;
    const float* src; int col0, stride;
    if (n0 < ROW_K)      { src = Wq; col0 = n0;         stride = NH * HD; }
    else if (n0 < ROW_V) { src = Wk; col0 = n0 - ROW_K; stride = NKVH * HD; }
    else                 { src = Wv; col0 = n0 - ROW_V; stride = NKVH * HD; }
    const int c = threadIdx.x & 31, r0 = threadIdx.x >> 5;
    #pragma unroll
    for (int r = r0; r < 32; r += 8)
        tile[r][c] = src[(size_t)(k0 + r) * stride + col0 + c];
    __syncthreads();
    #pragma unroll
    for (int r = r0; r < 32; r += 8)
        WT[(size_t)(n0 + r) * HIDDEN + k0 + c] = f2bf(tile[c][r]);
}

// ---------- W [K][N] fp32 -> WT [N][K] bf16 (for Wo) ----------
__global__ void transpose_w(const float* __restrict__ W, unsigned short* __restrict__ WT,
                            int K, int N)
{
    __shared__ float tile[32][33];
    const int k0 = blockIdx.y * 32, n0 = blockIdx.x * 32;
    const int c = threadIdx.x & 31, r0 = threadIdx.x >> 5;
    #pragma unroll
    for (int r = r0; r < 32; r += 8)
        tile[r][c] = W[(size_t)(k0 + r) * N + n0 + c];
    __syncthreads();
    #pragma unroll
    for (int r = r0; r < 32; r += 8)
        WT[(size_t)(n0 + r) * K + k0 + c] = f2bf(tile[c][r]);
}

__global__ void pack_bias(const float* __restrict__ bq, const float* __restrict__ bk,
                          const float* __restrict__ bv, float* __restrict__ o)
{
    int i = blockIdx.x * 256 + threadIdx.x;
    if (i < ROW_K) o[i] = bq[i];
    else if (i < ROW_V) o[i] = bk[i - ROW_K];
    else if (i < QKV_N) o[i] = bv[i - ROW_V];
}

// ---------- RoPE on packed qkv (q scaled by 1/sqrt(D)), fp32 math ----------
__global__ void rope_kernel(unsigned short* __restrict__ qkv, const int* __restrict__ pos,
                            const float* __restrict__ invf)
{
    const int tok = blockIdx.x * 4 + (threadIdx.x >> 6);
    const int f = threadIdx.x & 63;
    const float p = (float)pos[tok];
    const float ang = p * invf[f];
    const float c = cosf(ang), s = sinf(ang);
    const float SC = 0.08838834764831845f;
    unsigned short* row = qkv + (size_t)tok * QKV_N;
    #pragma unroll
    for (int h = 0; h < NH; ++h) {
        unsigned short* u = row + h * HD;
        const float x1 = bf2f(u[f]), x2 = bf2f(u[f + 64]);
        u[f]      = f2bf((x1 * c - x2 * s) * SC);
        u[f + 64] = f2bf((x2 * c + x1 * s) * SC);
    }
    #pragma unroll
    for (int h = 0; h < NKVH; ++h) {
        unsigned short* u = row + ROW_K + h * HD;
        const float x1 = bf2f(u[f]), x2 = bf2f(u[f + 64]);
        u[f]      = f2bf(x1 * c - x2 * s);
        u[f + 64] = f2bf(x2 * c + x1 * s);
    }
}

// ============ 8-phase 256xBN MFMA GEMM (T3+T4+T5, T1) ============
// C[M][N] = A[M][K] * BT[N][K]^T (+bias). BM=256, BK=64, 8 waves (2m x 4n).
// MODE 0: BN=256, bf16 out stride QKV_N, bias, V cols written transposed to vt
// MODE 1: BN=128, f32 out stride HIDDEN, no bias
// LDS per operand buf: [2 half][8 subtile][8 kblk][16 row][8 k] (linear, conflict-free)
template<int MODE>
__global__ __launch_bounds__(512, 2) void gemm8(const unsigned short* __restrict__ A,
                                                const unsigned short* __restrict__ BT,
                                                const float* __restrict__ bias,
                                                void* __restrict__ Cout,
                                                unsigned short* __restrict__ vt,
                                                int N, int K)
{
    constexpr int BN    = (MODE == 0) ? 256 : 128;
    constexpr int NPH   = (MODE == 0) ? 2 : 1;        // n-subtiles per nh half per wave
    constexpr int BHALF = (MODE == 0) ? 16384 : 8192; // bytes per B half-tile
    constexpr int ABUF  = 32768;
    constexpr int BBUF  = 2 * BHALF;
    constexpr int BOFF  = 2 * ABUF;
    __shared__ __align__(16) unsigned char lds[BOFF + 2 * BBUF];

    const int tid = threadIdx.x, lane = tid & 63, w = tid >> 6;
    const int wm = w >> 2, wn = w & 3;
    const int lr = lane & 15, lk = lane >> 4;

    const int NTN = N / BN;
    const int cpx = gridDim.x >> 3;
    const int bid = blockIdx.x;
    const int wg = (bid & 7) * cpx + (bid >> 3);      // XCD swizzle (nwg % 8 == 0)
    const int brow = (wg / NTN) * 256, bcol = (wg % NTN) * BN;

    // per-thread staging constants (rt=w, kb=i*4+lk, lrow=lr)
    const size_t aRow = (size_t)(brow + w * 16 + lr) * K + lk * 8;
    size_t bRow;
    if constexpr (MODE == 0) bRow = (size_t)(bcol + w * 16 + lr) * K + lk * 8;
    else                     bRow = (size_t)(bcol + (w >> 1) * 16 + lr) * K + ((w & 1) * 4 + lk) * 8;
    const int dstA = w * 2048 + lane * 16;
    const int dstB = (MODE == 0) ? dstA : (w * 1024 + lane * 16);

    auto stA = [&](int kt, int h, int b) {
        const unsigned short* s = A + aRow + (size_t)h * 128 * K + kt * 64;
        unsigned char* d = lds + b * ABUF + h * 16384 + dstA;
        gload16(s, d);
        gload16(s + 32, d + 1024);
    };
    auto stB = [&](int kt, int h, int b) {
        const unsigned short* s = BT + bRow + (size_t)h * (BN / 2) * K + kt * 64;
        unsigned char* d = lds + BOFF + b * BBUF + h * BHALF + dstB;
        gload16(s, d);
        if constexpr (MODE == 0) gload16(s + 32, d + 1024);
    };

    const int fragOff = lk * 256 + lr * 16;
    auto ldA = [&](int b, int mh, int m, int kk) -> bf16x8 {
        return *(const bf16x8*)(lds + b * ABUF + mh * 16384 + (wm * 4 + m) * 2048
                                + kk * 1024 + fragOff);
    };
    auto ldB = [&](int b, int nh, int n, int kk) -> bf16x8 {
        const int sub = (MODE == 0) ? (wn * 2 + n) : wn;
        return *(const bf16x8*)(lds + BOFF + b * BBUF + nh * BHALF + sub * 2048
                                + kk * 1024 + fragOff);
    };

    f32x4 acc[8][2 * NPH];
    #pragma unroll
    for (int i = 0; i < 8; ++i)
        #pragma unroll
        for (int j = 0; j < 2 * NPH; ++j)
            acc[i][j] = f32x4{0.f, 0.f, 0.f, 0.f};

    const int NT = K >> 6;

    // prologue: K0 fully (4 half-tiles) + {A0,B0,B1} of K1
    stA(0, 0, 0); stA(0, 1, 0); stB(0, 0, 0); stB(0, 1, 0);
    stA(1, 0, 1); stB(1, 0, 1); stB(1, 1, 1);
    if constexpr (MODE == 0) asm volatile("s_waitcnt vmcnt(6)" ::: "memory");
    else                     asm volatile("s_waitcnt vmcnt(4)" ::: "memory");
    BAR();

    for (int kt = 0; kt < NT; ++kt) {
        const int b = kt & 1;
        bf16x8 af[4][2], bfr[2][NPH][2];

        // ---- ph0: read A-h0 (8) + B-h0; stage A1(kt+1) -> buf b^1
        #pragma unroll
        for (int m = 0; m < 4; ++m) {
            af[m][0] = ldA(b, 0, m, 0);
            af[m][1] = ldA(b, 0, m, 1);
        }
        #pragma unroll
        for (int n = 0; n < NPH; ++n) {
            bfr[0][n][0] = ldB(b, 0, n, 0);
            bfr[0][n][1] = ldB(b, 0, n, 1);
        }
        if (kt + 1 < NT) stA(kt + 1, 1, b ^ 1);
        BAR();
        __builtin_amdgcn_s_setprio(1);
        #pragma unroll
        for (int m = 0; m < 4; ++m)
            #pragma unroll
            for (int n = 0; n < NPH; ++n)
                #pragma unroll
                for (int kk = 0; kk < 2; ++kk)
                    acc[m][n] = __builtin_amdgcn_mfma_f32_16x16x32_bf16(
                        af[m][kk], bfr[0][n][kk], acc[m][n], 0, 0, 0);
        __builtin_amdgcn_s_setprio(0);
        BAR();

        // ---- ph1: read B-h1; stage A0(kt+2) -> buf b
        #pragma unroll
        for (int n = 0; n < NPH; ++n) {
            bfr[1][n][0] = ldB(b, 1, n, 0);
            bfr[1][n][1] = ldB(b, 1, n, 1);
        }
        if (kt + 2 < NT) stA(kt + 2, 0, b);
        BAR();
        __builtin_amdgcn_s_setprio(1);
        #pragma unroll
        for (int m = 0; m < 4; ++m)
            #pragma unroll
            for (int n = 0; n < NPH; ++n)
                #pragma unroll
                for (int kk = 0; kk < 2; ++kk)
                    acc[m][NPH + n] = __builtin_amdgcn_mfma_f32_16x16x32_bf16(
                        af[m][kk], bfr[1][n][kk], acc[m][NPH + n], 0, 0, 0);
        __builtin_amdgcn_s_setprio(0);
        BAR();

        // ---- ph2: read A-h1 (8); stage B0(kt+2) -> buf b
        #pragma unroll
        for (int m = 0; m < 4; ++m) {
            af[m][0] = ldA(b, 1, m, 0);
            af[m][1] = ldA(b, 1, m, 1);
        }
        if (kt + 2 < NT) stB(kt + 2, 0, b);
        BAR();
        __builtin_amdgcn_s_setprio(1);
        #pragma unroll
        for (int m = 0; m < 4; ++m)
            #pragma unroll
            for (int n = 0; n < NPH; ++n)
                #pragma unroll
                for (int kk = 0; kk < 2; ++kk)
                    acc[4 + m][n] = __builtin_amdgcn_mfma_f32_16x16x32_bf16(
                        af[m][kk], bfr[0][n][kk], acc[4 + m][n], 0, 0, 0);
        __builtin_amdgcn_s_setprio(0);
        BAR();

        // ---- ph3: stage B1(kt+2) -> buf b; counted vmcnt (once per K-tile)
        if (kt + 2 < NT) stB(kt + 2, 1, b);
        if (kt < NT - 2) {
            if constexpr (MODE == 0) asm volatile("s_waitcnt vmcnt(6)" ::: "memory");
            else                     asm volatile("s_waitcnt vmcnt(4)" ::: "memory");
        } else {
            asm volatile("s_waitcnt vmcnt(0)" ::: "memory");
        }
        BAR();
        __builtin_amdgcn_s_setprio(1);
        #pragma unroll
        for (int m = 0; m < 4; ++m)
            #pragma unroll
            for (int n = 0; n < NPH; ++n)
                #pragma unroll
                for (int kk = 0; kk < 2; ++kk)
                    acc[4 + m][NPH + n] = __builtin_amdgcn_mfma_f32_16x16x32_bf16(
                        af[m][kk], bfr[1][n][kk], acc[4 + m][NPH + n], 0, 0, 0);
        __builtin_amdgcn_s_setprio(0);
        BAR();
    }

    // epilogue
    #pragma unroll
    for (int ms = 0; ms < 8; ++ms) {
        const int row = brow + (ms >> 2) * 128 + wm * 64 + (ms & 3) * 16 + lk * 4;
        #pragma unroll
        for (int ns = 0; ns < 2 * NPH; ++ns) {
            int col;
            if constexpr (MODE == 0)
                col = bcol + (ns >> 1) * 128 + wn * 32 + (ns & 1) * 16 + lr;
            else
                col = bcol + ns * 64 + wn * 16 + lr;
            const float bbv = (MODE == 0) ? bias[col] : 0.f;
            if (MODE == 0 && col >= ROW_V) {
                ushort4 o;
                o.x = f2bf(acc[ms][ns][0] + bbv);
                o.y = f2bf(acc[ms][ns][1] + bbv);
                o.z = f2bf(acc[ms][ns][2] + bbv);
                o.w = f2bf(acc[ms][ns][3] + bbv);
                *(ushort4*)&vt[(size_t)(col - ROW_V) * T_TOK + row] = o;
            } else {
                #pragma unroll
                for (int j = 0; j < 4; ++j) {
                    const float vv = acc[ms][ns][j] + bbv;
                    if (MODE == 0)
                        ((unsigned short*)Cout)[(size_t)(row + j) * QKV_N + col] = f2bf(vv);
                    else
                        ((float*)Cout)[(size_t)(row + j) * HIDDEN + col] = vv;
                }
            }
        }
    }
}

// ---------- varlen causal GQA flash attention ----------
// Swapped-operand MFMA: S^T = mfma(K,Q), O^T = mfma(V^T, P^T). P in registers.
__global__ __launch_bounds__(256) void attn_mfma(const unsigned short* __restrict__ qkv,
                                                 const unsigned short* __restrict__ vt,
                                                 const int* __restrict__ cu,
                                                 unsigned short* __restrict__ ob)
{
    __shared__ __align__(16) unsigned short Klds[2][4096]; // [st2][kk4][lk4][lr16][8]
    __shared__ __align__(16) unsigned short Vlds[2][4096]; // [dt8][lk4][lr16][8]

    const int tid = threadIdx.x;
    const int l = tid & 63, w = tid >> 6;
    const int lr = l & 15, lk = l >> 4;

    const int bid = blockIdx.x;
    const int h = bid >> 6;
    const int qb = (bid + 37 * (bid >> 6)) & 63;   // balance swizzle
    const int q0 = qb * 64;
    const int kvh = h >> 3;

    bf16x8 aq[4];
    #pragma unroll
    for (int kk = 0; kk < 4; ++kk)
        aq[kk] = *(const bf16x8*)&qkv[(size_t)(q0 + w * 16 + lr) * QKV_N + h * HD + kk * 32 + lk * 8];

    const int qg = q0 + w * 16 + lr;
    int seg_lo = 0, seg_last = 0, sb = 0;
    #pragma unroll
    for (int x = 1; x < NSEG; ++x) {
        const int cx = cu[x];
        seg_lo   = (cx <= qg)      ? cx : seg_lo;
        seg_last = (cx <= q0 + 63) ? cx : seg_last;
        sb       = (cx <= q0)      ? cx : sb;
    }
    sb &= ~31;

    const int lr_s = tid & 15, lk_s = (tid >> 4) & 3, w_s = tid >> 6;
    const unsigned short* kSrc0 = qkv + (size_t)(sb + lr_s) * QKV_N + ROW_K + kvh * HD + w_s * 32 + lk_s * 8;
    const unsigned short* kSrc1 = kSrc0 + (size_t)16 * QKV_N;
    const unsigned short* vSrc0 = vt + (size_t)(kvh * HD + w_s * 16 + lr_s) * T_TOK + sb + lk_s * 8;
    const unsigned short* vSrc1 = vSrc0 + (size_t)64 * T_TOK;

    float m_r = -1e30f, l_r = 0.f;
    f32x4 oacc[8];
    #pragma unroll
    for (int d = 0; d < 8; ++d) oacc[d] = f32x4{0.f, 0.f, 0.f, 0.f};

    const int nt = ((q0 + 63 - sb) >> 5) + 1;

    gload16(kSrc0, &Klds[0][tid * 8]);
    gload16(kSrc1, &Klds[0][2048 + tid * 8]);
    gload16(vSrc0, &Vlds[0][tid * 8]);
    gload16(vSrc1, &Vlds[0][2048 + tid * 8]);
    __syncthreads();

    int buf = 0;
    for (int t = 0; t < nt; ++t) {
        const int s0 = sb + t * 32;
        kSrc0 += 32 * QKV_N; kSrc1 += 32 * QKV_N;
        vSrc0 += 32;         vSrc1 += 32;
        if (t + 1 < nt) {
            gload16(kSrc0, &Klds[buf ^ 1][tid * 8]);
            gload16(kSrc1, &Klds[buf ^ 1][2048 + tid * 8]);
            gload16(vSrc0, &Vlds[buf ^ 1][tid * 8]);
            gload16(vSrc1, &Vlds[buf ^ 1][2048 + tid * 8]);
        }

        f32x4 sacc[2];
        sacc[0] = f32x4{0.f, 0.f, 0.f, 0.f};
        sacc[1] = f32x4{0.f, 0.f, 0.f, 0.f};
        #pragma unroll
        for (int kk = 0; kk < 4; ++kk) {
            bf16x8 ak0 = *(const bf16x8*)&Klds[buf][kk * 512 + lk * 128 + lr * 8];
            bf16x8 ak1 = *(const bf16x8*)&Klds[buf][2048 + kk * 512 + lk * 128 + lr * 8];
            sacc[0] = __builtin_amdgcn_mfma_f32_16x16x32_bf16(ak0, aq[kk], sacc[0], 0, 0, 0);
            sacc[1] = __builtin_amdgcn_mfma_f32_16x16x32_bf16(ak1, aq[kk], sacc[1], 0, 0, 0);
        }

        float x[8];
        #pragma unroll
        for (int st = 0; st < 2; ++st)
            #pragma unroll
            for (int jj = 0; jj < 4; ++jj)
                x[st * 4 + jj] = sacc[st][jj];

        const bool fast = (s0 >= seg_last) && (s0 + 31 <= q0);
        if (!fast) {
            #pragma unroll
            for (int st = 0; st < 2; ++st)
                #pragma unroll
                for (int jj = 0; jj < 4; ++jj) {
                    const int sg = s0 + st * 16 + lk * 4 + jj;
                    const bool vld = (sg >= seg_lo) && (sg <= qg);
                    x[st * 4 + jj] = vld ? x[st * 4 + jj] : -3e38f;
                }
        }

        float mx = fmaxf(fmaxf(fmaxf(x[0], x[1]), fmaxf(x[2], x[3])),
                         fmaxf(fmaxf(x[4], x[5]), fmaxf(x[6], x[7])));
        mx = fmaxf(mx, __shfl_xor(mx, 16));
        mx = fmaxf(mx, __shfl_xor(mx, 32));
        const float mn = fmaxf(m_r, mx);
        const float al = __expf(m_r - mn);
        float p[8], ps = 0.f;
        #pragma unroll
        for (int i = 0; i < 8; ++i) { p[i] = __expf(x[i] - mn); ps += p[i]; }
        ps += __shfl_xor(ps, 16);
        ps += __shfl_xor(ps, 32);
        l_r = l_r * al + ps;
        m_r = mn;

        #pragma unroll
        for (int dt = 0; dt < 8; ++dt) {
            oacc[dt][0] *= al; oacc[dt][1] *= al;
            oacc[dt][2] *= al; oacc[dt][3] *= al;
        }

        int u00 = ((int)f2bf(p[1]) << 16) | f2bf(p[0]);
        int u01 = ((int)f2bf(p[3]) << 16) | f2bf(p[2]);
        int u10 = ((int)f2bf(p[5]) << 16) | f2bf(p[4]);
        int u11 = ((int)f2bf(p[7]) << 16) | f2bf(p[6]);

        const int srcA = (lk & 1) * 32 + lr;
        const int srcB = srcA + 16;
        const bool hi = (lk & 2) != 0;
        int a0 = __shfl(u00, srcA), b0 = __shfl(u10, srcA);
        int a1 = __shfl(u01, srcA), b1 = __shfl(u11, srcA);
        int a2 = __shfl(u00, srcB), b2 = __shfl(u10, srcB);
        int a3 = __shfl(u01, srcB), b3 = __shfl(u11, srcB);
        union { int wds[4]; bf16x8 v; } pf;
        pf.wds[0] = hi ? b0 : a0;
        pf.wds[1] = hi ? b1 : a1;
        pf.wds[2] = hi ? b2 : a2;
        pf.wds[3] = hi ? b3 : a3;

        #pragma unroll
        for (int dt = 0; dt < 8; ++dt) {
            bf16x8 av = *(const bf16x8*)&Vlds[buf][dt * 512 + lk * 128 + lr * 8];
            oacc[dt] = __builtin_amdgcn_mfma_f32_16x16x32_bf16(av, pf.v, oacc[dt], 0, 0, 0);
        }
        __syncthreads();
        buf ^= 1;
    }

    const float inv = 1.f / l_r;
    #pragma unroll
    for (int dt = 0; dt < 8; ++dt) {
        ushort4 o;
        o.x = f2bf(oacc[dt][0] * inv);
        o.y = f2bf(oacc[dt][1] * inv);
        o.z = f2bf(oacc[dt][2] * inv);
        o.w = f2bf(oacc[dt][3] * inv);
        *(ushort4*)&ob[(size_t)qg * (NH * HD) + h * HD + dt * 16 + lk * 4] = o;
    }
}

extern "C" void kernel_launch(void* const* d_in, const int* in_sizes, int n_in,
                              void* d_out, int out_size, void* d_ws, size_t ws_size,
                              hipStream_t stream)
{
    const float* hs       = (const float*)d_in[0];
    const int*   pos      = (const int*)d_in[1];
    const int*   cu       = (const int*)d_in[2];
    const float* inv_freq = (const float*)d_in[3];
    const float* Wq       = (const float*)d_in[4];
    const float* bq       = (const float*)d_in[5];
    const float* Wk       = (const float*)d_in[6];
    const float* bk       = (const float*)d_in[7];
    const float* Wv       = (const float*)d_in[8];
    const float* bv       = (const float*)d_in[9];
    const float* Wo       = (const float*)d_in[10];
    float* out = (float*)d_out;

    unsigned short* hsb   = (unsigned short*)d_ws;          //  8,388,608
    unsigned short* wqkvT = hsb + 8388608;                  //  5,242,880
    unsigned short* wot   = wqkvT + 5242880;                //  4,194,304
    unsigned short* qkvb  = wot + 4194304;                  // 10,485,760
    unsigned short* vtb   = qkvb + 10485760;                //  1,048,576
    unsigned short* obb   = vtb + 1048576;                  //  8,388,608
    float* bqkv = (float*)(obb + 8388608);                  //  2,560 floats

    conv_bf16<<<8192, 256, 0, stream>>>(hs, hsb, T_TOK * HIDDEN);
    transpose_wqkv<<<dim3(QKV_N / 32, HIDDEN / 32), 256, 0, stream>>>(Wq, Wk, Wv, wqkvT);
    transpose_w<<<dim3(HIDDEN / 32, HIDDEN / 32), 256, 0, stream>>>(Wo, wot, NH * HD, HIDDEN);
    pack_bias<<<10, 256, 0, stream>>>(bq, bk, bv, bqkv);

    gemm8<0><<<dim3((T_TOK / 256) * (QKV_N / 256)), 512, 0, stream>>>(
        hsb, wqkvT, bqkv, qkvb, vtb, QKV_N, HIDDEN);

    rope_kernel<<<dim3(T_TOK / 4), 256, 0, stream>>>(qkvb, pos, inv_freq);

    attn_mfma<<<dim3(64 * NH), 256, 0, stream>>>(qkvb, vtb, cu, obb);

    gemm8<1><<<dim3((T_TOK / 256) * (HIDDEN / 128)), 512, 0, stream>>>(
        obb, wot, nullptr, out, nullptr, HIDDEN, NH * HD);
}